// Round 4
// baseline (3266.799 us; speedup 1.0000x reference)
//
#include <hip/hip_runtime.h>
#include <hip/hip_bf16.h>

// Problem constants: B=4, L=2048, d_model=d_value=512, H=8, E=64, d4=2048.
// All external inputs and the output are fp32 (verified R3: bf16 reads of the
// input gave NaN -> inputs are fp32; bf16 writes of the output gave error >
// stub-zero error -> output is fp32).

__device__ __forceinline__ void storeOut(float* p, float v) { *p = v; }
__device__ __forceinline__ void storeOut(__hip_bfloat16* p, float v) { *p = __float2bfloat16(v); }

__device__ __forceinline__ float ldA(const float* p, size_t i) { return p[i]; }
__device__ __forceinline__ float ldA(const __hip_bfloat16* p, size_t i) { return __bfloat162float(p[i]); }

// ---------------------------------------------------------------------------
// GEMM: C[M,N] = A[M,K] @ W[N,K]^T + bias[N]  (optional ReLU)
// A: fp32 or bf16(ws). W/bias: fp32. C: fp32 or bf16(ws). fp32 accumulate.
// Block 256 threads, 64x64 output tile, 4x4 per thread, K-tile 16.
// ---------------------------------------------------------------------------
template <typename TA, typename TOUT, bool RELU>
__global__ __launch_bounds__(256) void gemm_bt(const TA* __restrict__ A,
                                               const float* __restrict__ W,
                                               const float* __restrict__ bias,
                                               TOUT* __restrict__ C,
                                               int M, int N, int K)
{
    __shared__ float As[16][68];
    __shared__ float Ws[16][68];
    const int t  = threadIdx.x;
    const int tx = t & 15;
    const int ty = t >> 4;
    const int m0 = blockIdx.y * 64;
    const int n0 = blockIdx.x * 64;

    float acc[4][4] = {};

    for (int k0 = 0; k0 < K; k0 += 16) {
        const int r  = t >> 2;
        const int kb = (t & 3) * 4;
        #pragma unroll
        for (int c = 0; c < 4; c++)
            As[kb + c][r] = ldA(A, (size_t)(m0 + r) * K + k0 + kb + c);
        #pragma unroll
        for (int c = 0; c < 4; c++)
            Ws[kb + c][r] = W[(size_t)(n0 + r) * K + k0 + kb + c];
        __syncthreads();

        #pragma unroll
        for (int kk = 0; kk < 16; kk++) {
            float a[4], w[4];
            #pragma unroll
            for (int i = 0; i < 4; i++) a[i] = As[kk][ty * 4 + i];
            #pragma unroll
            for (int j = 0; j < 4; j++) w[j] = Ws[kk][tx * 4 + j];
            #pragma unroll
            for (int i = 0; i < 4; i++)
                #pragma unroll
                for (int j = 0; j < 4; j++)
                    acc[i][j] = fmaf(a[i], w[j], acc[i][j]);
        }
        __syncthreads();
    }

    #pragma unroll
    for (int j = 0; j < 4; j++) {
        const float bj = bias[n0 + tx * 4 + j];
        #pragma unroll
        for (int i = 0; i < 4; i++) {
            float c = acc[i][j] + bj;
            if (RELU) c = fmaxf(c, 0.f);
            storeOut(&C[(size_t)(m0 + ty * 4 + i) * N + n0 + tx * 4 + j], c);
        }
    }
}

// ---------------------------------------------------------------------------
// Transpose K projection: [B,S,H,64] -> [B,H,64,S].
// ---------------------------------------------------------------------------
__global__ __launch_bounds__(256) void transpose_k(const float* __restrict__ Kp,
                                                   float* __restrict__ Kt,
                                                   int L, int H)
{
    __shared__ float tile[64][65];
    const int s0 = blockIdx.x * 64;
    const int bh = blockIdx.y;
    const int b  = bh / H;
    const int h  = bh % H;
    const int tx = threadIdx.x;   // 0..63
    const int ty = threadIdx.y;   // 0..3
    #pragma unroll
    for (int i = 0; i < 16; i++) {
        const int sl = ty * 16 + i;
        tile[sl][tx] = Kp[((size_t)(b * L + s0 + sl) * H + h) * 64 + tx];
    }
    __syncthreads();
    #pragma unroll
    for (int i = 0; i < 16; i++) {
        const int el = ty * 16 + i;
        Kt[((size_t)bh * 64 + el) * L + s0 + tx] = tile[tx][el];
    }
}

// ---------------------------------------------------------------------------
// Causal attention, online softmax, register-only (shfl broadcasts, no LDS).
// One wave = 4 consecutive query rows of one (b,h). lane = E-dim for Q/V/O,
// lane = key index for scores. All intermediates finite.
// Q: [B,L,H,64], Kt: [B,H,64,L], V: [B,L,H,64], O: [B,L,H,64] (fp32).
// ---------------------------------------------------------------------------
__global__ __launch_bounds__(256) void attn_causal(const float* __restrict__ Q,
                                                   const float* __restrict__ Kt,
                                                   const float* __restrict__ V,
                                                   float* __restrict__ O,
                                                   int B, int L)
{
    const int lane  = threadIdx.x & 63;
    const int wid   = threadIdx.x >> 6;
    const int tiles = L / 16;                 // 16 rows per block (4 waves x 4 rows)
    const int bh    = blockIdx.x / tiles;
    const int tile  = blockIdx.x % tiles;
    const int b     = bh >> 3;                // H = 8
    const int h     = bh & 7;
    const int q0    = tile * 16 + wid * 4;

    const float* Kb = Kt + (size_t)bh * 64 * L;

    float q[4], m[4], l[4], o[4];
    #pragma unroll
    for (int r = 0; r < 4; r++) {
        q[r] = Q[((size_t)(b * L + q0 + r) * 8 + h) * 64 + lane];
        m[r] = -1e30f;
        l[r] = 0.f;
        o[r] = 0.f;
    }

    const int jmax = q0 + 3;
    for (int jb = 0; jb <= jmax; jb += 64) {
        const int j = jb + lane;              // j < L always (jb <= q0, q0+63 < L)

        float s[4] = {0.f, 0.f, 0.f, 0.f};
        #pragma unroll
        for (int e = 0; e < 64; e++) {
            const float kv = Kb[(size_t)e * L + j];       // coalesced over lanes
            #pragma unroll
            for (int r = 0; r < 4; r++)
                s[r] = fmaf(__shfl(q[r], e), kv, s[r]);   // broadcast Q[row r][e]
        }

        float p[4];
        #pragma unroll
        for (int r = 0; r < 4; r++) {
            float sv = s[r] * 0.125f;                 // 1/sqrt(64)
            if (j > q0 + r) sv = -1e30f;              // causal mask (finite)
            float cm = sv;
            #pragma unroll
            for (int off = 32; off > 0; off >>= 1)
                cm = fmaxf(cm, __shfl_xor(cm, off));
            const float mn = fmaxf(m[r], cm);
            const float al = __expf(m[r] - mn);       // arg <= 0
            p[r] = __expf(sv - mn);                   // arg <= 0
            float ps = p[r];
            #pragma unroll
            for (int off = 32; off > 0; off >>= 1)
                ps += __shfl_xor(ps, off);
            l[r] = l[r] * al + ps;
            o[r] *= al;
            m[r] = mn;
        }

        const int nj = (jmax - jb + 1 < 64) ? (jmax - jb + 1) : 64;
        for (int jj = 0; jj < nj; jj++) {
            const float vv = V[((size_t)(b * L + jb + jj) * 8 + h) * 64 + lane];
            o[0] = fmaf(__shfl(p[0], jj), vv, o[0]);
            o[1] = fmaf(__shfl(p[1], jj), vv, o[1]);
            o[2] = fmaf(__shfl(p[2], jj), vv, o[2]);
            o[3] = fmaf(__shfl(p[3], jj), vv, o[3]);
        }
    }

    #pragma unroll
    for (int r = 0; r < 4; r++)
        O[((size_t)(b * L + q0 + r) * 8 + h) * 64 + lane] = o[r] / l[r];   // l >= 1
}

// ---------------------------------------------------------------------------
// LayerNorm over last dim (512): out = (x - mu) * rsqrt(max(var,0)+1e-5)*g + b
// x = f1 [+ f2] [+ rb]. All fp32. Block = 256 threads = one row.
// ---------------------------------------------------------------------------
__global__ __launch_bounds__(256) void layernorm_k(const float* __restrict__ f1,
                                                   const float* __restrict__ f2,
                                                   const float* __restrict__ rb,
                                                   const float* __restrict__ g,
                                                   const float* __restrict__ bb,
                                                   float* __restrict__ out)
{
    const int row = blockIdx.x;
    const int t   = threadIdx.x;
    const size_t base = (size_t)row * 512;
    const int i0 = t * 2;

    float a0 = f1[base + i0], a1 = f1[base + i0 + 1];
    if (f2) { a0 += f2[base + i0]; a1 += f2[base + i0 + 1]; }
    if (rb) { a0 += rb[base + i0]; a1 += rb[base + i0 + 1]; }

    float s = a0 + a1, ss = a0 * a0 + a1 * a1;
    #pragma unroll
    for (int off = 32; off > 0; off >>= 1) {
        s  += __shfl_xor(s, off);
        ss += __shfl_xor(ss, off);
    }
    __shared__ float red[16];
    const int lane = t & 63, wid = t >> 6;
    if (lane == 0) { red[wid] = s; red[8 + wid] = ss; }
    __syncthreads();
    if (t == 0) {
        const float S  = red[0] + red[1] + red[2] + red[3];
        const float SS = red[8] + red[9] + red[10] + red[11];
        const float mu = S * (1.f / 512.f);
        const float var = SS * (1.f / 512.f) - mu * mu;
        red[0] = mu;
        red[1] = rsqrtf(fmaxf(var, 0.f) + 1e-5f);
    }
    __syncthreads();
    const float mu = red[0], rstd = red[1];
    out[base + i0]     = (a0 - mu) * rstd * g[i0]     + bb[i0];
    out[base + i0 + 1] = (a1 - mu) * rstd * g[i0 + 1] + bb[i0 + 1];
}

// ---------------------------------------------------------------------------
extern "C" void kernel_launch(void* const* d_in, const int* in_sizes, int n_in,
                              void* d_out, int out_size, void* d_ws, size_t ws_size,
                              hipStream_t stream)
{
    const float* q   = (const float*)d_in[0];
    const float* k   = (const float*)d_in[1];
    const float* v   = (const float*)d_in[2];
    const float* Wq  = (const float*)d_in[3];
    const float* bq  = (const float*)d_in[4];
    const float* Wk  = (const float*)d_in[5];
    const float* bk  = (const float*)d_in[6];
    const float* Wv  = (const float*)d_in[7];
    const float* bv  = (const float*)d_in[8];
    const float* Wo  = (const float*)d_in[9];
    const float* bo  = (const float*)d_in[10];
    const float* Wc1 = (const float*)d_in[11];
    const float* bc1 = (const float*)d_in[12];
    const float* Wc2 = (const float*)d_in[13];
    const float* bc2 = (const float*)d_in[14];
    const float* g1  = (const float*)d_in[15];
    const float* b1  = (const float*)d_in[16];
    const float* g2  = (const float*)d_in[17];
    const float* b2  = (const float*)d_in[18];
    const float* Wl  = (const float*)d_in[19];
    const float* bl  = (const float*)d_in[20];
    float* out = (float*)d_out;

    const int B = 4, L = 2048, H = 8;
    const int M = B * L;                        // 8192 rows
    const size_t SZ = (size_t)M * 512;          // one [M,512] fp32 slab (16.78 MB)

    float* ws = (float*)d_ws;
    // 5-slab liveness map (83.9 MB):
    float* Qp = ws + 0 * SZ;                    // Q proj        -> later A2 -> X2
    float* Kp = ws + 1 * SZ;                    // K proj        -> later X1
    float* Vp = ws + 2 * SZ;                    // V proj        -> later H1 (bf16, slots 2-3)
    float* Kt = ws + 3 * SZ;                    // K^T [B,H,64,L]
    float* A1 = ws + 4 * SZ;                    // attention out -> later Y2
    float* A2 = Qp;
    float* X1 = Kp;
    __hip_bfloat16* H1 = (__hip_bfloat16*)(ws + 2 * SZ);   // [M,2048] bf16
    float* Y2 = A1;
    float* X2 = Qp;

    const dim3 blk(256);

    // 1-3: Q/K/V projections  [M,512] = in @ W^T + b
    gemm_bt<float, float, false><<<dim3(8, 128), blk, 0, stream>>>(q, Wq, bq, Qp, M, 512, 512);
    gemm_bt<float, float, false><<<dim3(8, 128), blk, 0, stream>>>(k, Wk, bk, Kp, M, 512, 512);
    gemm_bt<float, float, false><<<dim3(8, 128), blk, 0, stream>>>(v, Wv, bv, Vp, M, 512, 512);

    // 4: K -> [B,H,64,L]
    transpose_k<<<dim3(L / 64, B * H), dim3(64, 4), 0, stream>>>(Kp, Kt, L, H);

    // 5: causal attention
    attn_causal<<<dim3(B * H * (L / 16)), blk, 0, stream>>>(Qp, Kt, Vp, A1, B, L);

    // 6: att @ Wo^T + bo   (Qp dead -> A2)
    gemm_bt<float, float, false><<<dim3(8, 128), blk, 0, stream>>>(A1, Wo, bo, A2, M, 512, 512);

    // 7: x = LN(v + attO)  (Kp dead -> X1)
    layernorm_k<<<dim3(M), blk, 0, stream>>>(A2, nullptr, v, g1, b1, X1);

    // 8: h1 = relu(x @ Wc1^T + bc1)  [M,2048] bf16  (Vp,Kt dead -> H1)
    gemm_bt<float, __hip_bfloat16, true><<<dim3(32, 128), blk, 0, stream>>>(X1, Wc1, bc1, H1, M, 2048, 512);

    // 9: y2 = h1 @ Wc2^T + bc2  [M,512]  (A1 dead -> Y2)
    gemm_bt<__hip_bfloat16, float, false><<<dim3(8, 128), blk, 0, stream>>>(H1, Wc2, bc2, Y2, M, 512, 2048);

    // 10: x2 = LN(x + y2)  (A2 dead -> X2)
    layernorm_k<<<dim3(M), blk, 0, stream>>>(X1, Y2, nullptr, g2, b2, X2);

    // 11: out = x2 @ Wl^T + bl  (fp32 out)
    gemm_bt<float, float, false><<<dim3(8, 128), blk, 0, stream>>>(X2, Wl, bl, out, M, 512, 512);
}

// Round 5
// 1034.481 us; speedup vs baseline: 3.1579x; 3.1579x over previous
//
#include <hip/hip_runtime.h>
#include <hip/hip_bf16.h>

// Problem constants: B=4, L=2048, d_model=d_value=512, H=8, E=64, d4=2048.
// External inputs/output are fp32 (verified R3/R4). Attention runs in bf16 MFMA.

typedef __attribute__((ext_vector_type(8))) short sh8;    // 8 bf16 (A/B frag)
typedef __attribute__((ext_vector_type(4))) float f32x4;  // C/D frag

__device__ __forceinline__ void storeOut(float* p, float v) { *p = v; }
__device__ __forceinline__ void storeOut(__hip_bfloat16* p, float v) { *p = __float2bfloat16(v); }

__device__ __forceinline__ float ldA(const float* p, size_t i) { return p[i]; }
__device__ __forceinline__ float ldA(const __hip_bfloat16* p, size_t i) { return __bfloat162float(p[i]); }

// ---------------------------------------------------------------------------
// GEMM: C[M,N] = A[M,K] @ W[N,K]^T + bias[N]  (optional ReLU)
// A: fp32 or bf16(ws). W/bias: fp32. C: fp32 or bf16(ws). fp32 accumulate.
// ---------------------------------------------------------------------------
template <typename TA, typename TOUT, bool RELU>
__global__ __launch_bounds__(256) void gemm_bt(const TA* __restrict__ A,
                                               const float* __restrict__ W,
                                               const float* __restrict__ bias,
                                               TOUT* __restrict__ C,
                                               int M, int N, int K)
{
    __shared__ float As[16][68];
    __shared__ float Ws[16][68];
    const int t  = threadIdx.x;
    const int tx = t & 15;
    const int ty = t >> 4;
    const int m0 = blockIdx.y * 64;
    const int n0 = blockIdx.x * 64;

    float acc[4][4] = {};

    for (int k0 = 0; k0 < K; k0 += 16) {
        const int r  = t >> 2;
        const int kb = (t & 3) * 4;
        #pragma unroll
        for (int c = 0; c < 4; c++)
            As[kb + c][r] = ldA(A, (size_t)(m0 + r) * K + k0 + kb + c);
        #pragma unroll
        for (int c = 0; c < 4; c++)
            Ws[kb + c][r] = W[(size_t)(n0 + r) * K + k0 + kb + c];
        __syncthreads();

        #pragma unroll
        for (int kk = 0; kk < 16; kk++) {
            float a[4], w[4];
            #pragma unroll
            for (int i = 0; i < 4; i++) a[i] = As[kk][ty * 4 + i];
            #pragma unroll
            for (int j = 0; j < 4; j++) w[j] = Ws[kk][tx * 4 + j];
            #pragma unroll
            for (int i = 0; i < 4; i++)
                #pragma unroll
                for (int j = 0; j < 4; j++)
                    acc[i][j] = fmaf(a[i], w[j], acc[i][j]);
        }
        __syncthreads();
    }

    #pragma unroll
    for (int j = 0; j < 4; j++) {
        const float bj = bias[n0 + tx * 4 + j];
        #pragma unroll
        for (int i = 0; i < 4; i++) {
            float c = acc[i][j] + bj;
            if (RELU) c = fmaxf(c, 0.f);
            storeOut(&C[(size_t)(m0 + ty * 4 + i) * N + n0 + tx * 4 + j], c);
        }
    }
}

// ---------------------------------------------------------------------------
// Transpose V projection (bf16): [B,S,H,64] -> [B,H,64,S].
// ---------------------------------------------------------------------------
__global__ __launch_bounds__(256) void transpose_v(const unsigned short* __restrict__ Vb,
                                                   unsigned short* __restrict__ Vt,
                                                   int L, int H)
{
    __shared__ unsigned short tile[64][65];
    const int s0 = blockIdx.x * 64;
    const int bh = blockIdx.y;
    const int b  = bh / H;
    const int h  = bh % H;
    const int tx = threadIdx.x;   // 0..63
    const int ty = threadIdx.y;   // 0..3
    #pragma unroll
    for (int i = 0; i < 16; i++) {
        const int sl = ty * 16 + i;
        tile[sl][tx] = Vb[((size_t)(b * L + s0 + sl) * H + h) * 64 + tx];
    }
    __syncthreads();
    #pragma unroll
    for (int i = 0; i < 16; i++) {
        const int el = ty * 16 + i;
        Vt[((size_t)bh * 64 + el) * L + s0 + tx] = tile[tx][el];
    }
}

// ---------------------------------------------------------------------------
// MFMA flash attention (causal). Block = 256 thr = 4 waves = 64 query rows.
// Wave w owns queries [q0 + 16w, q0 + 16w + 15]. Per 64-key tile:
//   S (16x64) = Q16x64 @ K^T via 4 n-tiles x 2 K-halves of mfma_16x16x32_bf16
//   online softmax in C-layout (col=lane&15, row=quad*4+reg)  [m89/m91]
//   P -> per-wave LDS round-trip into A-layout (A[m=lane&15][k=quad*8+j]) [m120]
//   O += P @ V via 8 MFMA against Vt LDS tile.
// Qb/Kb: [B,L,H,64] bf16;  Vt: [B*H,64,L] bf16;  O: [B,L,H,64] fp32.
// ---------------------------------------------------------------------------
__global__ __launch_bounds__(256) void attn_mfma(const unsigned short* __restrict__ Qb,
                                                 const unsigned short* __restrict__ Kb,
                                                 const unsigned short* __restrict__ Vt,
                                                 float* __restrict__ O,
                                                 int B, int L)
{
    __shared__ short Ks[64][72];      // [key][e]   (+8 pad; 144B row = 16B-aligned)
    __shared__ short Vs[64][72];      // [e][key]
    __shared__ short Ps[4][16][72];   // per wave: [qrow][key]

    const int qt   = (gridDim.x - 1) - blockIdx.x;  // heavy blocks first
    const int bh   = blockIdx.y;
    const int b    = bh >> 3;                        // H = 8
    const int h    = bh & 7;
    const int t    = threadIdx.x;
    const int w    = t >> 6;
    const int lane = t & 63;
    const int quad = lane >> 4;
    const int col  = lane & 15;

    const int q0 = qt * 64;
    const int qw = q0 + w * 16;

    // Q A-fragments (held in registers for the whole kernel):
    // A[m=lane&15][k=quad*8+j], k = e in [0,32) and [32,64)
    sh8 qf[2];
    {
        const size_t qbase = ((size_t)(b * L + qw + col) * 8 + h) * 64;
        qf[0] = *(const sh8*)(Qb + qbase + quad * 8);
        qf[1] = *(const sh8*)(Qb + qbase + 32 + quad * 8);
    }

    f32x4 Oacc[4];
    #pragma unroll
    for (int nt = 0; nt < 4; nt++) Oacc[nt] = (f32x4){0.f, 0.f, 0.f, 0.f};
    float mrow[4] = {-1e30f, -1e30f, -1e30f, -1e30f};
    float lrow[4] = {0.f, 0.f, 0.f, 0.f};

    for (int kt = 0; kt <= qt; kt++) {
        const int k0 = kt * 64;

        // ---- stage K tile [key][e] and V tile [e][key] (16 bf16 per thread each)
        {
            const int r  = t >> 2;           // 0..63
            const int c0 = (t & 3) * 16;
            const unsigned short* src = Kb + ((size_t)(b * L + k0 + r) * 8 + h) * 64 + c0;
            *(int4*)&Ks[r][c0]     = *(const int4*)src;          // 8 bf16
            *(int4*)&Ks[r][c0 + 8] = *(const int4*)(src + 8);
            const unsigned short* vsrc = Vt + ((size_t)bh * 64 + r) * L + k0 + c0;
            *(int4*)&Vs[r][c0]     = *(const int4*)vsrc;
            *(int4*)&Vs[r][c0 + 8] = *(const int4*)(vsrc + 8);
        }
        __syncthreads();

        // ---- S = Q @ K^T  (C-layout: row=quad*4+reg, col=lane&15 per n-tile)
        f32x4 s[4];
        const f32x4 zz = {0.f, 0.f, 0.f, 0.f};
        #pragma unroll
        for (int nt = 0; nt < 4; nt++) {
            const int key = nt * 16 + col;
            sh8 kf0 = *(const sh8*)&Ks[key][quad * 8];
            sh8 kf1 = *(const sh8*)&Ks[key][32 + quad * 8];
            f32x4 acc = __builtin_amdgcn_mfma_f32_16x16x32_bf16(qf[0], kf0, zz, 0, 0, 0);
            acc       = __builtin_amdgcn_mfma_f32_16x16x32_bf16(qf[1], kf1, acc, 0, 0, 0);
            s[nt] = acc;
        }

        // ---- online softmax (per reg = per query row)
        #pragma unroll
        for (int reg = 0; reg < 4; reg++) {
            const int qrow = qw + quad * 4 + reg;
            float sv[4];
            #pragma unroll
            for (int nt = 0; nt < 4; nt++) {
                float x = s[nt][reg] * 0.125f;               // 1/sqrt(64)
                if (k0 + nt * 16 + col > qrow) x = -1e30f;   // causal mask
                sv[nt] = x;
            }
            float cm = fmaxf(fmaxf(sv[0], sv[1]), fmaxf(sv[2], sv[3]));
            #pragma unroll
            for (int off = 8; off > 0; off >>= 1)
                cm = fmaxf(cm, __shfl_xor(cm, off));         // 16-lane row group
            const float mn = fmaxf(mrow[reg], cm);
            const float al = __expf(mrow[reg] - mn);
            float p[4], psum = 0.f;
            #pragma unroll
            for (int nt = 0; nt < 4; nt++) { p[nt] = __expf(sv[nt] - mn); psum += p[nt]; }
            #pragma unroll
            for (int off = 8; off > 0; off >>= 1)
                psum += __shfl_xor(psum, off);
            lrow[reg] = lrow[reg] * al + psum;
            mrow[reg] = mn;
            #pragma unroll
            for (int nt = 0; nt < 4; nt++) Oacc[nt][reg] *= al;
            #pragma unroll
            for (int nt = 0; nt < 4; nt++)
                Ps[w][quad * 4 + reg][nt * 16 + col] =
                    (short)__bfloat16_as_ushort(__float2bfloat16(p[nt]));
        }

        // ---- O += P @ V   (A = P from per-wave LDS, B^T = Vs[e][key])
        #pragma unroll
        for (int half = 0; half < 2; half++) {
            sh8 pf = *(const sh8*)&Ps[w][col][half * 32 + quad * 8];
            #pragma unroll
            for (int nt = 0; nt < 4; nt++) {
                sh8 vf = *(const sh8*)&Vs[nt * 16 + col][half * 32 + quad * 8];
                Oacc[nt] = __builtin_amdgcn_mfma_f32_16x16x32_bf16(pf, vf, Oacc[nt], 0, 0, 0);
            }
        }
        __syncthreads();   // protect Ks/Vs before next tile's staging
    }

    // ---- epilogue: O /= l, store fp32 [B,L,H,64]
    #pragma unroll
    for (int reg = 0; reg < 4; reg++) {
        const int qrow = qw + quad * 4 + reg;
        const float inv = 1.f / lrow[reg];
        #pragma unroll
        for (int nt = 0; nt < 4; nt++)
            O[((size_t)(b * L + qrow) * 8 + h) * 64 + nt * 16 + col] = Oacc[nt][reg] * inv;
    }
}

// ---------------------------------------------------------------------------
// LayerNorm over last dim (512). x = f1 [+ f2] [+ rb]. All fp32.
// ---------------------------------------------------------------------------
__global__ __launch_bounds__(256) void layernorm_k(const float* __restrict__ f1,
                                                   const float* __restrict__ f2,
                                                   const float* __restrict__ rb,
                                                   const float* __restrict__ g,
                                                   const float* __restrict__ bb,
                                                   float* __restrict__ out)
{
    const int row = blockIdx.x;
    const int t   = threadIdx.x;
    const size_t base = (size_t)row * 512;
    const int i0 = t * 2;

    float a0 = f1[base + i0], a1 = f1[base + i0 + 1];
    if (f2) { a0 += f2[base + i0]; a1 += f2[base + i0 + 1]; }
    if (rb) { a0 += rb[base + i0]; a1 += rb[base + i0 + 1]; }

    float s = a0 + a1, ss = a0 * a0 + a1 * a1;
    #pragma unroll
    for (int off = 32; off > 0; off >>= 1) {
        s  += __shfl_xor(s, off);
        ss += __shfl_xor(ss, off);
    }
    __shared__ float red[16];
    const int lane = t & 63, wid = t >> 6;
    if (lane == 0) { red[wid] = s; red[8 + wid] = ss; }
    __syncthreads();
    if (t == 0) {
        const float S  = red[0] + red[1] + red[2] + red[3];
        const float SS = red[8] + red[9] + red[10] + red[11];
        const float mu = S * (1.f / 512.f);
        const float var = SS * (1.f / 512.f) - mu * mu;
        red[0] = mu;
        red[1] = rsqrtf(fmaxf(var, 0.f) + 1e-5f);
    }
    __syncthreads();
    const float mu = red[0], rstd = red[1];
    out[base + i0]     = (a0 - mu) * rstd * g[i0]     + bb[i0];
    out[base + i0 + 1] = (a1 - mu) * rstd * g[i0 + 1] + bb[i0 + 1];
}

// ---------------------------------------------------------------------------
extern "C" void kernel_launch(void* const* d_in, const int* in_sizes, int n_in,
                              void* d_out, int out_size, void* d_ws, size_t ws_size,
                              hipStream_t stream)
{
    const float* q   = (const float*)d_in[0];
    const float* k   = (const float*)d_in[1];
    const float* v   = (const float*)d_in[2];
    const float* Wq  = (const float*)d_in[3];
    const float* bq  = (const float*)d_in[4];
    const float* Wk  = (const float*)d_in[5];
    const float* bk  = (const float*)d_in[6];
    const float* Wv  = (const float*)d_in[7];
    const float* bv  = (const float*)d_in[8];
    const float* Wo  = (const float*)d_in[9];
    const float* bo  = (const float*)d_in[10];
    const float* Wc1 = (const float*)d_in[11];
    const float* bc1 = (const float*)d_in[12];
    const float* Wc2 = (const float*)d_in[13];
    const float* bc2 = (const float*)d_in[14];
    const float* g1  = (const float*)d_in[15];
    const float* b1  = (const float*)d_in[16];
    const float* g2  = (const float*)d_in[17];
    const float* b2  = (const float*)d_in[18];
    const float* Wl  = (const float*)d_in[19];
    const float* bl  = (const float*)d_in[20];
    float* out = (float*)d_out;

    const int B = 4, L = 2048, H = 8;
    const int M = B * L;                        // 8192
    const size_t SZ = (size_t)M * 512;          // one [M,512] fp32 slab (16.78 MB)

    float* ws = (float*)d_ws;
    // 5-slab liveness map (83.9 MB):
    __hip_bfloat16* Qb = (__hip_bfloat16*)(ws + 0 * SZ);   // slab0 lo
    __hip_bfloat16* Kb = Qb + SZ;                          // slab0 hi
    __hip_bfloat16* Vb = (__hip_bfloat16*)(ws + 1 * SZ);   // slab1 lo
    __hip_bfloat16* Vt = Vb + SZ;                          // slab1 hi
    float* A1 = ws + 2 * SZ;                               // attn out
    float* A2 = ws + 3 * SZ;                               // Wo out
    float* X1 = ws + 4 * SZ;                               // LN1 out (live to LN2)
    __hip_bfloat16* H1 = (__hip_bfloat16*)(ws + 2 * SZ);   // FFN hidden [M,2048] (slabs 2-3; A1,A2 dead)
    float* Y2 = ws + 0 * SZ;                               // FFN2 out (Qb/Kb dead)
    float* X2 = ws + 2 * SZ;                               // LN2 out (H1 dead)

    const dim3 blk(256);

    // 1-3: projections -> bf16
    gemm_bt<float, __hip_bfloat16, false><<<dim3(8, 128), blk, 0, stream>>>(q, Wq, bq, Qb, M, 512, 512);
    gemm_bt<float, __hip_bfloat16, false><<<dim3(8, 128), blk, 0, stream>>>(k, Wk, bk, Kb, M, 512, 512);
    gemm_bt<float, __hip_bfloat16, false><<<dim3(8, 128), blk, 0, stream>>>(v, Wv, bv, Vb, M, 512, 512);

    // 4: V -> [B,H,64,L] bf16
    transpose_v<<<dim3(L / 64, B * H), dim3(64, 4), 0, stream>>>(
        (const unsigned short*)Vb, (unsigned short*)Vt, L, H);

    // 5: MFMA flash attention
    attn_mfma<<<dim3(L / 64, B * H), blk, 0, stream>>>(
        (const unsigned short*)Qb, (const unsigned short*)Kb,
        (const unsigned short*)Vt, A1, B, L);

    // 6: att @ Wo^T + bo
    gemm_bt<float, float, false><<<dim3(8, 128), blk, 0, stream>>>(A1, Wo, bo, A2, M, 512, 512);

    // 7: x = LN(v + attO)
    layernorm_k<<<dim3(M), blk, 0, stream>>>(A2, nullptr, v, g1, b1, X1);

    // 8: h1 = relu(x @ Wc1^T + bc1)  [M,2048] bf16
    gemm_bt<float, __hip_bfloat16, true><<<dim3(32, 128), blk, 0, stream>>>(X1, Wc1, bc1, H1, M, 2048, 512);

    // 9: y2 = h1 @ Wc2^T + bc2  [M,512]
    gemm_bt<__hip_bfloat16, float, false><<<dim3(8, 128), blk, 0, stream>>>(H1, Wc2, bc2, Y2, M, 512, 2048);

    // 10: x2 = LN(x + y2)
    layernorm_k<<<dim3(M), blk, 0, stream>>>(X1, Y2, nullptr, g2, b2, X2);

    // 11: out = x2 @ Wl^T + bl (fp32)
    gemm_bt<float, float, false><<<dim3(8, 128), blk, 0, stream>>>(X2, Wl, bl, out, M, 512, 512);
}

// Round 6
// 512.072 us; speedup vs baseline: 6.3796x; 2.0202x over previous
//
#include <hip/hip_runtime.h>
#include <hip/hip_bf16.h>

// Problem constants: B=4, L=2048, d_model=d_value=512, H=8, E=64, d4=2048.
// External inputs/output fp32 (verified R3/R4). Internal compute: bf16 MFMA.

typedef __attribute__((ext_vector_type(8))) short sh8;    // 8 bf16 (A/B frag)
typedef __attribute__((ext_vector_type(4))) float f32x4;  // C/D frag

__device__ __forceinline__ void storeOut(float* p, float v) { *p = v; }
__device__ __forceinline__ void storeOut(__hip_bfloat16* p, float v) { *p = __float2bfloat16(v); }

// async global->LDS, 16 B per lane, wave-uniform LDS base (m97 pattern)
__device__ __forceinline__ void gl_lds16(const unsigned short* g, unsigned short* l) {
    __builtin_amdgcn_global_load_lds((const __attribute__((address_space(1))) void*)g,
                                     (__attribute__((address_space(3))) void*)l, 16, 0, 0);
}

// ---------------------------------------------------------------------------
// fp32 -> bf16 elementwise convert (n % 4 == 0)
// ---------------------------------------------------------------------------
__global__ __launch_bounds__(256) void f2b(const float* __restrict__ x,
                                           __hip_bfloat16* __restrict__ y, int n)
{
    const int i = (blockIdx.x * 256 + threadIdx.x) * 4;
    if (i < n) {
        const float4 v = *(const float4*)(x + i);
        y[i]     = __float2bfloat16(v.x);
        y[i + 1] = __float2bfloat16(v.y);
        y[i + 2] = __float2bfloat16(v.z);
        y[i + 3] = __float2bfloat16(v.w);
    }
}

// ---------------------------------------------------------------------------
// MFMA GEMM: C[M,N] = A[M,K](bf16) @ W[N,K](bf16)^T + bias[N](fp32), opt ReLU.
// 128x128 block tile, 4 waves (2x2), 64x64 per wave = 4x4 MFMA 16x16x32_bf16.
// BK=32. LDS kblock-major: slot(q=k/8, r) at linear (q*128+r)*16B -> staging is
// lane-contiguous (global_load_lds constraint) AND ds_read_b128 conflict-free
// (8 consecutive lanes span 128 B = 32 banks).
// ---------------------------------------------------------------------------
template <typename TOUT, bool RELU>
__global__ __launch_bounds__(256) void gemm_mfma(const unsigned short* __restrict__ A,
                                                 const unsigned short* __restrict__ W,
                                                 const float* __restrict__ bias,
                                                 TOUT* __restrict__ C,
                                                 int M, int N, int K)
{
    __shared__ unsigned short AsL[4096];   // 8 KB: [q:4][row:128][8 bf16]
    __shared__ unsigned short BsL[4096];
    const int t    = threadIdx.x;
    const int wave = t >> 6, lane = t & 63;
    const int quad = lane >> 4, col = lane & 15;
    const int wm   = wave >> 1, wn = wave & 1;
    const int m0   = blockIdx.y * 128, n0 = blockIdx.x * 128;

    f32x4 acc[4][4];
    #pragma unroll
    for (int mt = 0; mt < 4; mt++)
        #pragma unroll
        for (int nt = 0; nt < 4; nt++)
            acc[mt][nt] = (f32x4){0.f, 0.f, 0.f, 0.f};

    for (int k0 = 0; k0 < K; k0 += 32) {
        // ---- stage A,B tiles: 2 segments x (A,B) per wave, 1 KB per instr
        #pragma unroll
        for (int seg = 0; seg < 2; seg++) {
            const int s0 = seg * 256 + wave * 64;    // wave-uniform slot base
            const int s  = s0 + lane;
            const int r  = s & 127;
            const int q  = s >> 7;
            gl_lds16(A + (size_t)(m0 + r) * K + k0 + q * 8, &AsL[s0 * 8]);
            gl_lds16(W + (size_t)(n0 + r) * K + k0 + q * 8, &BsL[s0 * 8]);
        }
        __syncthreads();   // drains vmcnt -> staging visible

        sh8 af[4], bf[4];
        #pragma unroll
        for (int mt = 0; mt < 4; mt++)
            af[mt] = *(const sh8*)&AsL[(quad * 128 + wm * 64 + mt * 16 + col) * 8];
        #pragma unroll
        for (int nt = 0; nt < 4; nt++)
            bf[nt] = *(const sh8*)&BsL[(quad * 128 + wn * 64 + nt * 16 + col) * 8];
        #pragma unroll
        for (int mt = 0; mt < 4; mt++)
            #pragma unroll
            for (int nt = 0; nt < 4; nt++)
                acc[mt][nt] = __builtin_amdgcn_mfma_f32_16x16x32_bf16(af[mt], bf[nt], acc[mt][nt], 0, 0, 0);
        __syncthreads();   // protect LDS before next tile's staging
    }

    // ---- epilogue: C row = quad*4+reg, col = lane&15  [m89/m91]
    #pragma unroll
    for (int nt = 0; nt < 4; nt++) {
        const int cn = n0 + wn * 64 + nt * 16 + col;
        const float bj = bias[cn];
        #pragma unroll
        for (int mt = 0; mt < 4; mt++) {
            const int rm = m0 + wm * 64 + mt * 16 + quad * 4;
            #pragma unroll
            for (int reg = 0; reg < 4; reg++) {
                float cv = acc[mt][nt][reg] + bj;
                if (RELU) cv = fmaxf(cv, 0.f);
                storeOut(&C[(size_t)(rm + reg) * N + cn], cv);
            }
        }
    }
}

// ---------------------------------------------------------------------------
// Transpose V projection (bf16): [B,S,H,64] -> [B,H,64,S].
// ---------------------------------------------------------------------------
__global__ __launch_bounds__(256) void transpose_v(const unsigned short* __restrict__ Vb,
                                                   unsigned short* __restrict__ Vt,
                                                   int L, int H)
{
    __shared__ unsigned short tile[64][65];
    const int s0 = blockIdx.x * 64;
    const int bh = blockIdx.y;
    const int b  = bh / H;
    const int h  = bh % H;
    const int tx = threadIdx.x;   // 0..63
    const int ty = threadIdx.y;   // 0..3
    #pragma unroll
    for (int i = 0; i < 16; i++) {
        const int sl = ty * 16 + i;
        tile[sl][tx] = Vb[((size_t)(b * L + s0 + sl) * H + h) * 64 + tx];
    }
    __syncthreads();
    #pragma unroll
    for (int i = 0; i < 16; i++) {
        const int el = ty * 16 + i;
        Vt[((size_t)bh * 64 + el) * L + s0 + tx] = tile[tx][el];
    }
}

// ---------------------------------------------------------------------------
// MFMA flash attention (causal). Block = 256 thr = 4 waves = 64 query rows.
// (verified R5; output now bf16 to feed the Wo MFMA gemm directly)
// ---------------------------------------------------------------------------
__global__ __launch_bounds__(256) void attn_mfma(const unsigned short* __restrict__ Qb,
                                                 const unsigned short* __restrict__ Kb,
                                                 const unsigned short* __restrict__ Vt,
                                                 __hip_bfloat16* __restrict__ O,
                                                 int B, int L)
{
    __shared__ short Ks[64][72];      // [key][e]
    __shared__ short Vs[64][72];      // [e][key]
    __shared__ short Ps[4][16][72];   // per wave: [qrow][key]

    const int qt   = (gridDim.x - 1) - blockIdx.x;  // heavy blocks first
    const int bh   = blockIdx.y;
    const int b    = bh >> 3;                        // H = 8
    const int h    = bh & 7;
    const int t    = threadIdx.x;
    const int w    = t >> 6;
    const int lane = t & 63;
    const int quad = lane >> 4;
    const int col  = lane & 15;

    const int q0 = qt * 64;
    const int qw = q0 + w * 16;

    sh8 qf[2];
    {
        const size_t qbase = ((size_t)(b * L + qw + col) * 8 + h) * 64;
        qf[0] = *(const sh8*)(Qb + qbase + quad * 8);
        qf[1] = *(const sh8*)(Qb + qbase + 32 + quad * 8);
    }

    f32x4 Oacc[4];
    #pragma unroll
    for (int nt = 0; nt < 4; nt++) Oacc[nt] = (f32x4){0.f, 0.f, 0.f, 0.f};
    float mrow[4] = {-1e30f, -1e30f, -1e30f, -1e30f};
    float lrow[4] = {0.f, 0.f, 0.f, 0.f};

    for (int kt = 0; kt <= qt; kt++) {
        const int k0 = kt * 64;
        {
            const int r  = t >> 2;
            const int c0 = (t & 3) * 16;
            const unsigned short* src = Kb + ((size_t)(b * L + k0 + r) * 8 + h) * 64 + c0;
            *(int4*)&Ks[r][c0]     = *(const int4*)src;
            *(int4*)&Ks[r][c0 + 8] = *(const int4*)(src + 8);
            const unsigned short* vsrc = Vt + ((size_t)bh * 64 + r) * L + k0 + c0;
            *(int4*)&Vs[r][c0]     = *(const int4*)vsrc;
            *(int4*)&Vs[r][c0 + 8] = *(const int4*)(vsrc + 8);
        }
        __syncthreads();

        f32x4 s[4];
        const f32x4 zz = {0.f, 0.f, 0.f, 0.f};
        #pragma unroll
        for (int nt = 0; nt < 4; nt++) {
            const int key = nt * 16 + col;
            sh8 kf0 = *(const sh8*)&Ks[key][quad * 8];
            sh8 kf1 = *(const sh8*)&Ks[key][32 + quad * 8];
            f32x4 acc = __builtin_amdgcn_mfma_f32_16x16x32_bf16(qf[0], kf0, zz, 0, 0, 0);
            acc       = __builtin_amdgcn_mfma_f32_16x16x32_bf16(qf[1], kf1, acc, 0, 0, 0);
            s[nt] = acc;
        }

        #pragma unroll
        for (int reg = 0; reg < 4; reg++) {
            const int qrow = qw + quad * 4 + reg;
            float sv[4];
            #pragma unroll
            for (int nt = 0; nt < 4; nt++) {
                float x = s[nt][reg] * 0.125f;
                if (k0 + nt * 16 + col > qrow) x = -1e30f;
                sv[nt] = x;
            }
            float cm = fmaxf(fmaxf(sv[0], sv[1]), fmaxf(sv[2], sv[3]));
            #pragma unroll
            for (int off = 8; off > 0; off >>= 1)
                cm = fmaxf(cm, __shfl_xor(cm, off));
            const float mn = fmaxf(mrow[reg], cm);
            const float al = __expf(mrow[reg] - mn);
            float p[4], psum = 0.f;
            #pragma unroll
            for (int nt = 0; nt < 4; nt++) { p[nt] = __expf(sv[nt] - mn); psum += p[nt]; }
            #pragma unroll
            for (int off = 8; off > 0; off >>= 1)
                psum += __shfl_xor(psum, off);
            lrow[reg] = lrow[reg] * al + psum;
            mrow[reg] = mn;
            #pragma unroll
            for (int nt = 0; nt < 4; nt++) Oacc[nt][reg] *= al;
            #pragma unroll
            for (int nt = 0; nt < 4; nt++)
                Ps[w][quad * 4 + reg][nt * 16 + col] =
                    (short)__bfloat16_as_ushort(__float2bfloat16(p[nt]));
        }

        #pragma unroll
        for (int half = 0; half < 2; half++) {
            sh8 pf = *(const sh8*)&Ps[w][col][half * 32 + quad * 8];
            #pragma unroll
            for (int nt = 0; nt < 4; nt++) {
                sh8 vf = *(const sh8*)&Vs[nt * 16 + col][half * 32 + quad * 8];
                Oacc[nt] = __builtin_amdgcn_mfma_f32_16x16x32_bf16(pf, vf, Oacc[nt], 0, 0, 0);
            }
        }
        __syncthreads();
    }

    #pragma unroll
    for (int reg = 0; reg < 4; reg++) {
        const int qrow = qw + quad * 4 + reg;
        const float inv = 1.f / lrow[reg];
        #pragma unroll
        for (int nt = 0; nt < 4; nt++)
            O[((size_t)(b * L + qrow) * 8 + h) * 64 + nt * 16 + col] =
                __float2bfloat16(Oacc[nt][reg] * inv);
    }
}

// ---------------------------------------------------------------------------
// LayerNorm over last dim (512). x = f1 [+ f2] [+ rb]. Dual output:
// out32 (fp32, nullable) and out16 (bf16, nullable).
// ---------------------------------------------------------------------------
__global__ __launch_bounds__(256) void layernorm_k(const float* __restrict__ f1,
                                                   const float* __restrict__ f2,
                                                   const float* __restrict__ rb,
                                                   const float* __restrict__ g,
                                                   const float* __restrict__ bb,
                                                   float* __restrict__ out32,
                                                   __hip_bfloat16* __restrict__ out16)
{
    const int row = blockIdx.x;
    const int t   = threadIdx.x;
    const size_t base = (size_t)row * 512;
    const int i0 = t * 2;

    float a0 = f1[base + i0], a1 = f1[base + i0 + 1];
    if (f2) { a0 += f2[base + i0]; a1 += f2[base + i0 + 1]; }
    if (rb) { a0 += rb[base + i0]; a1 += rb[base + i0 + 1]; }

    float s = a0 + a1, ss = a0 * a0 + a1 * a1;
    #pragma unroll
    for (int off = 32; off > 0; off >>= 1) {
        s  += __shfl_xor(s, off);
        ss += __shfl_xor(ss, off);
    }
    __shared__ float red[16];
    const int lane = t & 63, wid = t >> 6;
    if (lane == 0) { red[wid] = s; red[8 + wid] = ss; }
    __syncthreads();
    if (t == 0) {
        const float S  = red[0] + red[1] + red[2] + red[3];
        const float SS = red[8] + red[9] + red[10] + red[11];
        const float mu = S * (1.f / 512.f);
        const float var = SS * (1.f / 512.f) - mu * mu;
        red[0] = mu;
        red[1] = rsqrtf(fmaxf(var, 0.f) + 1e-5f);
    }
    __syncthreads();
    const float mu = red[0], rstd = red[1];
    const float y0 = (a0 - mu) * rstd * g[i0]     + bb[i0];
    const float y1 = (a1 - mu) * rstd * g[i0 + 1] + bb[i0 + 1];
    if (out32) { out32[base + i0] = y0; out32[base + i0 + 1] = y1; }
    if (out16) { out16[base + i0] = __float2bfloat16(y0); out16[base + i0 + 1] = __float2bfloat16(y1); }
}

// ---------------------------------------------------------------------------
extern "C" void kernel_launch(void* const* d_in, const int* in_sizes, int n_in,
                              void* d_out, int out_size, void* d_ws, size_t ws_size,
                              hipStream_t stream)
{
    const float* q   = (const float*)d_in[0];
    const float* k   = (const float*)d_in[1];
    const float* v   = (const float*)d_in[2];
    const float* Wq  = (const float*)d_in[3];
    const float* bq  = (const float*)d_in[4];
    const float* Wk  = (const float*)d_in[5];
    const float* bk  = (const float*)d_in[6];
    const float* Wv  = (const float*)d_in[7];
    const float* bv  = (const float*)d_in[8];
    const float* Wo  = (const float*)d_in[9];
    const float* bo  = (const float*)d_in[10];
    const float* Wc1 = (const float*)d_in[11];
    const float* bc1 = (const float*)d_in[12];
    const float* Wc2 = (const float*)d_in[13];
    const float* bc2 = (const float*)d_in[14];
    const float* g1  = (const float*)d_in[15];
    const float* b1  = (const float*)d_in[16];
    const float* g2  = (const float*)d_in[17];
    const float* b2  = (const float*)d_in[18];
    const float* Wl  = (const float*)d_in[19];
    const float* bl  = (const float*)d_in[20];
    float* out = (float*)d_out;

    const int B = 4, L = 2048, H = 8;
    const int M = B * L;                        // 8192

    // Byte-offset workspace map (peak 82.3 MB <= 83.9 MB avail; liveness-checked):
    char* base = (char*)d_ws;
    unsigned short* Wqb  = (unsigned short*)(base + 0);
    unsigned short* Wkb  = (unsigned short*)(base + 524288);
    unsigned short* Wvb  = (unsigned short*)(base + 1048576);
    unsigned short* Wob  = (unsigned short*)(base + 1572864);
    unsigned short* Wlb  = (unsigned short*)(base + 2097152);
    unsigned short* Wc1b = (unsigned short*)(base + 2621440);   // 2 MB
    unsigned short* Wc2b = (unsigned short*)(base + 4718592);   // 2 MB
    float*          X1   = (float*)(base + 6815744);            // fp32, to 23592960
    unsigned short* X1b  = (unsigned short*)(base + 23592960);  // to 31981568
    unsigned short* X2b  = (unsigned short*)(base + 23592960);  // reuse (X1b dead)
    unsigned short* H1   = (unsigned short*)(base + 31981568);  // 32 MB, to 65536000
    float*          Y2   = (float*)(base + 65536000);           // to 82313216
    float*          A2   = (float*)(base + 31981568);           // in H1 region
    unsigned short* A1   = (unsigned short*)(base + 48758784);  // in H1 region
    unsigned short* Qb   = (unsigned short*)(base + 57147392);  // in H1 region
    unsigned short* Kb   = (unsigned short*)(base + 65536000);  // in Y2 region
    unsigned short* Vt   = (unsigned short*)(base + 73924608);  // in Y2 region
    unsigned short* Vb   = (unsigned short*)(base + 6815744);   // in X1 region
    unsigned short* qb   = (unsigned short*)(base + 15204352);  // in X1 region
    unsigned short* kb   = (unsigned short*)(base + 23592960);  // in X1b region
    unsigned short* vb   = (unsigned short*)(base + 31981568);  // in A2/H1 region

    const dim3 blk(256);
    const int NQKV = M * 512;      // 4M elements

    // 0: fp32 -> bf16 converts (inputs + all weights)
    f2b<<<dim3(NQKV / 1024), blk, 0, stream>>>(q, (__hip_bfloat16*)qb, NQKV);
    f2b<<<dim3(NQKV / 1024), blk, 0, stream>>>(k, (__hip_bfloat16*)kb, NQKV);
    f2b<<<dim3(NQKV / 1024), blk, 0, stream>>>(v, (__hip_bfloat16*)vb, NQKV);
    f2b<<<dim3(256), blk, 0, stream>>>(Wq, (__hip_bfloat16*)Wqb, 512 * 512);
    f2b<<<dim3(256), blk, 0, stream>>>(Wk, (__hip_bfloat16*)Wkb, 512 * 512);
    f2b<<<dim3(256), blk, 0, stream>>>(Wv, (__hip_bfloat16*)Wvb, 512 * 512);
    f2b<<<dim3(256), blk, 0, stream>>>(Wo, (__hip_bfloat16*)Wob, 512 * 512);
    f2b<<<dim3(256), blk, 0, stream>>>(Wl, (__hip_bfloat16*)Wlb, 512 * 512);
    f2b<<<dim3(1024), blk, 0, stream>>>(Wc1, (__hip_bfloat16*)Wc1b, 2048 * 512);
    f2b<<<dim3(1024), blk, 0, stream>>>(Wc2, (__hip_bfloat16*)Wc2b, 512 * 2048);

    // 1-3: Q/K/V projections (bf16 MFMA, bf16 out)
    gemm_mfma<__hip_bfloat16, false><<<dim3(4, 64), blk, 0, stream>>>(qb, Wqb, bq, (__hip_bfloat16*)Qb, M, 512, 512);
    gemm_mfma<__hip_bfloat16, false><<<dim3(4, 64), blk, 0, stream>>>(kb, Wkb, bk, (__hip_bfloat16*)Kb, M, 512, 512);
    gemm_mfma<__hip_bfloat16, false><<<dim3(4, 64), blk, 0, stream>>>(vb, Wvb, bv, (__hip_bfloat16*)Vb, M, 512, 512);

    // 4: V -> [B,H,64,L] bf16
    transpose_v<<<dim3(L / 64, B * H), dim3(64, 4), 0, stream>>>(Vb, Vt, L, H);

    // 5: MFMA flash attention -> bf16
    attn_mfma<<<dim3(L / 64, B * H), blk, 0, stream>>>(Qb, Kb, Vt, (__hip_bfloat16*)A1, B, L);

    // 6: att @ Wo^T + bo -> fp32
    gemm_mfma<float, false><<<dim3(4, 64), blk, 0, stream>>>(A1, Wob, bo, A2, M, 512, 512);

    // 7: x = LN(v + attO) -> fp32 X1 (residual) + bf16 X1b (FFN1 A-operand)
    layernorm_k<<<dim3(M), blk, 0, stream>>>(A2, nullptr, v, g1, b1, X1, (__hip_bfloat16*)X1b);

    // 8: h1 = relu(x @ Wc1^T + bc1) -> bf16 [M,2048]
    gemm_mfma<__hip_bfloat16, true><<<dim3(16, 64), blk, 0, stream>>>(X1b, Wc1b, bc1, (__hip_bfloat16*)H1, M, 2048, 512);

    // 9: y2 = h1 @ Wc2^T + bc2 -> fp32
    gemm_mfma<float, false><<<dim3(4, 64), blk, 0, stream>>>(H1, Wc2b, bc2, Y2, M, 512, 2048);

    // 10: x2 = LN(x + y2) -> bf16 only
    layernorm_k<<<dim3(M), blk, 0, stream>>>(X1, Y2, nullptr, g2, b2, nullptr, (__hip_bfloat16*)X2b);

    // 11: out = x2 @ Wl^T + bl -> fp32 d_out
    gemm_mfma<float, false><<<dim3(4, 64), blk, 0, stream>>>(X2b, Wlb, bl, out, M, 512, 512);
}

// Round 7
// 442.754 us; speedup vs baseline: 7.3784x; 1.1566x over previous
//
#include <hip/hip_runtime.h>
#include <hip/hip_bf16.h>

// Problem constants: B=4, L=2048, d_model=d_value=512, H=8, E=64, d4=2048.
// External inputs/output fp32 (verified R3/R4). Internal compute: bf16 MFMA.

typedef __attribute__((ext_vector_type(8))) short sh8;    // 8 bf16 (A/B frag)
typedef __attribute__((ext_vector_type(4))) float f32x4;  // C/D frag

#define QSCALE 0.18033688011110543f   // 0.125 * log2(e): folded into Q projection

__device__ __forceinline__ void storeOut(float* p, float v) { *p = v; }
__device__ __forceinline__ void storeOut(__hip_bfloat16* p, float v) { *p = __float2bfloat16(v); }

// async global->LDS, 16 B per lane, wave-uniform LDS base (m97 pattern)
__device__ __forceinline__ void gl_lds16(const unsigned short* g, unsigned short* l) {
    __builtin_amdgcn_global_load_lds((const __attribute__((address_space(1))) void*)g,
                                     (__attribute__((address_space(3))) void*)l, 16, 0, 0);
}

// pack two fp32 into one dword of two bf16 (RNE)
__device__ __forceinline__ unsigned pk_bf16(float a, float b) {
    __hip_bfloat162 h = __float22bfloat162_rn(make_float2(a, b));
    return *(unsigned*)&h;
}

// ---------------------------------------------------------------------------
// Batched fp32 -> bf16 convert for q,k,v (grid.z selects tensor)
// ---------------------------------------------------------------------------
struct Cv3 { const float* s[3]; unsigned short* d[3]; };
__global__ __launch_bounds__(256) void conv_qkv(Cv3 p, int n)
{
    const int z = blockIdx.z;
    const int i = (blockIdx.x * 256 + threadIdx.x) * 4;
    if (i < n) {
        const float4 v = *(const float4*)(p.s[z] + i);
        uint2 u = make_uint2(pk_bf16(v.x, v.y), pk_bf16(v.z, v.w));
        *(uint2*)(p.d[z] + i) = u;
    }
}

// ---------------------------------------------------------------------------
// All 7 weights fp32 -> bf16 into one contiguous ws region.
// Segment order: Wq,Wk,Wv,Wo,Wl,Wc1,Wc2 (element bounds hardcoded).
// ---------------------------------------------------------------------------
__global__ __launch_bounds__(256) void conv_w(const float* s0, const float* s1,
                                              const float* s2, const float* s3,
                                              const float* s4, const float* s5,
                                              const float* s6,
                                              unsigned short* __restrict__ dst)
{
    const int i = (blockIdx.x * 256 + threadIdx.x) * 4;
    if (i >= 3407872) return;
    const float* s; int off;
    if      (i < 262144)  { s = s0; off = i; }
    else if (i < 524288)  { s = s1; off = i - 262144; }
    else if (i < 786432)  { s = s2; off = i - 524288; }
    else if (i < 1048576) { s = s3; off = i - 786432; }
    else if (i < 1310720) { s = s4; off = i - 1048576; }
    else if (i < 2359296) { s = s5; off = i - 1310720; }
    else                  { s = s6; off = i - 2359296; }
    const float4 v = *(const float4*)(s + off);
    *(uint2*)(dst + i) = make_uint2(pk_bf16(v.x, v.y), pk_bf16(v.z, v.w));
}

// ---------------------------------------------------------------------------
// MFMA GEMM 128x128 (m97 structure): C = A @ W^T + bias, opt ReLU. BK=32.
// ---------------------------------------------------------------------------
template <typename TOUT, bool RELU>
__global__ __launch_bounds__(256) void gemm_mfma(const unsigned short* __restrict__ A,
                                                 const unsigned short* __restrict__ W,
                                                 const float* __restrict__ bias,
                                                 TOUT* __restrict__ C,
                                                 int M, int N, int K)
{
    __shared__ unsigned short AsL[4096];   // [q:4][row:128][8]
    __shared__ unsigned short BsL[4096];
    const int t    = threadIdx.x;
    const int wave = t >> 6, lane = t & 63;
    const int quad = lane >> 4, col = lane & 15;
    const int wm   = wave >> 1, wn = wave & 1;
    const int m0   = blockIdx.y * 128, n0 = blockIdx.x * 128;

    f32x4 acc[4][4];
    #pragma unroll
    for (int mt = 0; mt < 4; mt++)
        #pragma unroll
        for (int nt = 0; nt < 4; nt++)
            acc[mt][nt] = (f32x4){0.f, 0.f, 0.f, 0.f};

    for (int k0 = 0; k0 < K; k0 += 32) {
        #pragma unroll
        for (int seg = 0; seg < 2; seg++) {
            const int s0 = seg * 256 + wave * 64;
            const int s  = s0 + lane;
            const int r  = s & 127, q = s >> 7;
            gl_lds16(A + (size_t)(m0 + r) * K + k0 + q * 8, &AsL[s0 * 8]);
            gl_lds16(W + (size_t)(n0 + r) * K + k0 + q * 8, &BsL[s0 * 8]);
        }
        __syncthreads();
        sh8 af[4], bf[4];
        #pragma unroll
        for (int mt = 0; mt < 4; mt++)
            af[mt] = *(const sh8*)&AsL[(quad * 128 + wm * 64 + mt * 16 + col) * 8];
        #pragma unroll
        for (int nt = 0; nt < 4; nt++)
            bf[nt] = *(const sh8*)&BsL[(quad * 128 + wn * 64 + nt * 16 + col) * 8];
        #pragma unroll
        for (int mt = 0; mt < 4; mt++)
            #pragma unroll
            for (int nt = 0; nt < 4; nt++)
                acc[mt][nt] = __builtin_amdgcn_mfma_f32_16x16x32_bf16(af[mt], bf[nt], acc[mt][nt], 0, 0, 0);
        __syncthreads();
    }
    #pragma unroll
    for (int nt = 0; nt < 4; nt++) {
        const int cn = n0 + wn * 64 + nt * 16 + col;
        const float bj = bias[cn];
        #pragma unroll
        for (int mt = 0; mt < 4; mt++) {
            const int rm = m0 + wm * 64 + mt * 16 + quad * 4;
            #pragma unroll
            for (int reg = 0; reg < 4; reg++) {
                float cv = acc[mt][nt][reg] + bj;
                if (RELU) cv = fmaxf(cv, 0.f);
                storeOut(&C[(size_t)(rm + reg) * N + cn], cv);
            }
        }
    }
}

// ---------------------------------------------------------------------------
// Batched QKV GEMM (grid.z = 0,1,2): same structure; per-z out scale
// (z=0 -> Q gets QSCALE folded into value+bias for exp2-domain attention).
// ---------------------------------------------------------------------------
struct QkvArg {
    const unsigned short *A0, *A1, *A2;
    const float *b0, *b1, *b2;
    unsigned short *C0, *C1, *C2;
};
__global__ __launch_bounds__(256) void gemm_qkv(QkvArg ar, const unsigned short* __restrict__ Wall,
                                                int M, int N, int K)
{
    const int z = blockIdx.z;
    const unsigned short* A = z == 0 ? ar.A0 : (z == 1 ? ar.A1 : ar.A2);
    const unsigned short* W = Wall + (size_t)z * 262144;
    const float* bias = z == 0 ? ar.b0 : (z == 1 ? ar.b1 : ar.b2);
    unsigned short* C = z == 0 ? ar.C0 : (z == 1 ? ar.C1 : ar.C2);
    const float scale = z == 0 ? QSCALE : 1.0f;

    __shared__ unsigned short AsL[4096];
    __shared__ unsigned short BsL[4096];
    const int t    = threadIdx.x;
    const int wave = t >> 6, lane = t & 63;
    const int quad = lane >> 4, col = lane & 15;
    const int wm   = wave >> 1, wn = wave & 1;
    const int m0   = blockIdx.y * 128, n0 = blockIdx.x * 128;

    f32x4 acc[4][4];
    #pragma unroll
    for (int mt = 0; mt < 4; mt++)
        #pragma unroll
        for (int nt = 0; nt < 4; nt++)
            acc[mt][nt] = (f32x4){0.f, 0.f, 0.f, 0.f};

    for (int k0 = 0; k0 < K; k0 += 32) {
        #pragma unroll
        for (int seg = 0; seg < 2; seg++) {
            const int s0 = seg * 256 + wave * 64;
            const int s  = s0 + lane;
            const int r  = s & 127, q = s >> 7;
            gl_lds16(A + (size_t)(m0 + r) * K + k0 + q * 8, &AsL[s0 * 8]);
            gl_lds16(W + (size_t)(n0 + r) * K + k0 + q * 8, &BsL[s0 * 8]);
        }
        __syncthreads();
        sh8 af[4], bf[4];
        #pragma unroll
        for (int mt = 0; mt < 4; mt++)
            af[mt] = *(const sh8*)&AsL[(quad * 128 + wm * 64 + mt * 16 + col) * 8];
        #pragma unroll
        for (int nt = 0; nt < 4; nt++)
            bf[nt] = *(const sh8*)&BsL[(quad * 128 + wn * 64 + nt * 16 + col) * 8];
        #pragma unroll
        for (int mt = 0; mt < 4; mt++)
            #pragma unroll
            for (int nt = 0; nt < 4; nt++)
                acc[mt][nt] = __builtin_amdgcn_mfma_f32_16x16x32_bf16(af[mt], bf[nt], acc[mt][nt], 0, 0, 0);
        __syncthreads();
    }
    #pragma unroll
    for (int nt = 0; nt < 4; nt++) {
        const int cn = n0 + wn * 64 + nt * 16 + col;
        const float bj = bias[cn];
        #pragma unroll
        for (int mt = 0; mt < 4; mt++) {
            const int rm = m0 + wm * 64 + mt * 16 + quad * 4;
            #pragma unroll
            for (int reg = 0; reg < 4; reg++)
                C[(size_t)(rm + reg) * N + cn] =
                    (unsigned short)__bfloat16_as_ushort(__float2bfloat16((acc[mt][nt][reg] + bj) * scale));
        }
    }
}

// ---------------------------------------------------------------------------
// MFMA GEMM 64x128 tile (2 blocks/CU for N=512 shapes). BK=32.
// Waves 2x2: wave tile 32 rows x 64 cols (2x4 MFMA).
// ---------------------------------------------------------------------------
template <typename TOUT, bool RELU>
__global__ __launch_bounds__(256) void gemm_mfma64(const unsigned short* __restrict__ A,
                                                   const unsigned short* __restrict__ W,
                                                   const float* __restrict__ bias,
                                                   TOUT* __restrict__ C,
                                                   int M, int N, int K)
{
    __shared__ unsigned short AsL[2048];   // [q:4][row:64][8]
    __shared__ unsigned short BsL[4096];   // [q:4][row:128][8]
    const int t    = threadIdx.x;
    const int wave = t >> 6, lane = t & 63;
    const int quad = lane >> 4, col = lane & 15;
    const int wm   = wave >> 1, wn = wave & 1;
    const int m0   = blockIdx.y * 64, n0 = blockIdx.x * 128;

    f32x4 acc[2][4];
    #pragma unroll
    for (int mt = 0; mt < 2; mt++)
        #pragma unroll
        for (int nt = 0; nt < 4; nt++)
            acc[mt][nt] = (f32x4){0.f, 0.f, 0.f, 0.f};

    for (int k0 = 0; k0 < K; k0 += 32) {
        {   // A: 256 slots, one seg; wave w stages e-block q=w
            gl_lds16(A + (size_t)(m0 + lane) * K + k0 + wave * 8, &AsL[(wave * 64) * 8]);
        }
        #pragma unroll
        for (int seg = 0; seg < 2; seg++) {
            const int s0 = seg * 256 + wave * 64;
            const int s  = s0 + lane;
            const int r  = s & 127, q = s >> 7;
            gl_lds16(W + (size_t)(n0 + r) * K + k0 + q * 8, &BsL[s0 * 8]);
        }
        __syncthreads();
        sh8 af[2], bf[4];
        #pragma unroll
        for (int mt = 0; mt < 2; mt++)
            af[mt] = *(const sh8*)&AsL[(quad * 64 + wm * 32 + mt * 16 + col) * 8];
        #pragma unroll
        for (int nt = 0; nt < 4; nt++)
            bf[nt] = *(const sh8*)&BsL[(quad * 128 + wn * 64 + nt * 16 + col) * 8];
        #pragma unroll
        for (int mt = 0; mt < 2; mt++)
            #pragma unroll
            for (int nt = 0; nt < 4; nt++)
                acc[mt][nt] = __builtin_amdgcn_mfma_f32_16x16x32_bf16(af[mt], bf[nt], acc[mt][nt], 0, 0, 0);
        __syncthreads();
    }
    #pragma unroll
    for (int nt = 0; nt < 4; nt++) {
        const int cn = n0 + wn * 64 + nt * 16 + col;
        const float bj = bias[cn];
        #pragma unroll
        for (int mt = 0; mt < 2; mt++) {
            const int rm = m0 + wm * 32 + mt * 16 + quad * 4;
            #pragma unroll
            for (int reg = 0; reg < 4; reg++) {
                float cv = acc[mt][nt][reg] + bj;
                if (RELU) cv = fmaxf(cv, 0.f);
                storeOut(&C[(size_t)(rm + reg) * N + cn], cv);
            }
        }
    }
}

// ---------------------------------------------------------------------------
// Transpose V projection (bf16): [B,S,H,64] -> [B,H,64,S].
// ---------------------------------------------------------------------------
__global__ __launch_bounds__(256) void transpose_v(const unsigned short* __restrict__ Vb,
                                                   unsigned short* __restrict__ Vt,
                                                   int L, int H)
{
    __shared__ unsigned short tile[64][65];
    const int s0 = blockIdx.x * 64;
    const int bh = blockIdx.y;
    const int b  = bh / H, h = bh % H;
    const int tx = threadIdx.x, ty = threadIdx.y;
    #pragma unroll
    for (int i = 0; i < 16; i++) {
        const int sl = ty * 16 + i;
        tile[sl][tx] = Vb[((size_t)(b * L + s0 + sl) * H + h) * 64 + tx];
    }
    __syncthreads();
    #pragma unroll
    for (int i = 0; i < 16; i++) {
        const int el = ty * 16 + i;
        Vt[((size_t)bh * 64 + el) * L + s0 + tx] = tile[tx][el];
    }
}

// ---------------------------------------------------------------------------
// MFMA flash attention v2 (causal). Block = 4 waves = 64 query rows.
// S^T layout: mfma(A=K,B=Q) -> lane owns ONE qrow (col) x 32 keys per round.
// exp2 domain (QSCALE pre-folded into Q projection). KT=128 keys/round,
// async k-major staging (conflict-free b128 reads), mask only last round.
// Qb/Kb: [B,L,H,64] bf16; Vt: [B*H,64,L] bf16; O: [B,L,H,64] bf16.
// ---------------------------------------------------------------------------
__global__ __launch_bounds__(256) void attn_mfma(const unsigned short* __restrict__ Qb,
                                                 const unsigned short* __restrict__ Kb,
                                                 const unsigned short* __restrict__ Vt,
                                                 __hip_bfloat16* __restrict__ O,
                                                 int L)
{
    __shared__ unsigned short Ks[8192];        // [q=e/8:8][key:128][8]  16 KB
    __shared__ unsigned short Vs[8192];        // [kq=key/8:16][e:64][8] 16 KB
    __shared__ unsigned short Ps[4][16][136];  // per wave [qrow:16][key:128+pad]

    const int qt   = (gridDim.x - 1) - blockIdx.x;   // heavy blocks first
    const int bh   = blockIdx.y;
    const int b    = bh >> 3, h = bh & 7;            // H = 8
    const int t    = threadIdx.x;
    const int w    = t >> 6, lane = t & 63;
    const int quad = lane >> 4, col = lane & 15;
    const int q0   = qt * 64;
    const int qw   = q0 + w * 16;
    const int qrow = qw + col;                       // this lane's query row

    // Q B-frag: B[n=qrow][k=e]  (values already scaled by QSCALE)
    sh8 qf[2];
    {
        const size_t qb = ((size_t)(b * L + qrow) * 8 + h) * 64;
        qf[0] = *(const sh8*)(Qb + qb + quad * 8);
        qf[1] = *(const sh8*)(Qb + qb + 32 + quad * 8);
    }

    f32x4 Oacc[4];
    #pragma unroll
    for (int nt = 0; nt < 4; nt++) Oacc[nt] = (f32x4){0.f, 0.f, 0.f, 0.f};
    float m = -1e30f, l = 0.f;

    const int R = (qt + 2) >> 1;                     // ceil((qt+1)/2) 128-key rounds
    for (int r = 0; r < R; r++) {
        const int k0 = r * 128;
        // ---- async staging: K (1024 slots) + Vt (1024 slots), 16 B/lane
        #pragma unroll
        for (int seg = 0; seg < 4; seg++) {
            const int s0 = seg * 256 + w * 64;
            const int s  = s0 + lane;
            {   const int q = s >> 7, key = s & 127;
                int row = k0 + key; if (row > L - 1) row = L - 1;
                gl_lds16(Kb + ((size_t)(b * L + row) * 8 + h) * 64 + q * 8, &Ks[s0 * 8]); }
            {   const int kq = s >> 6, e = s & 63;
                int kb = k0 + kq * 8; if (kb > L - 8) kb = L - 8;
                gl_lds16(Vt + ((size_t)bh * 64 + e) * L + kb, &Vs[s0 * 8]); }
        }
        __syncthreads();

        // ---- S^T: st[ntk][reg] = S[key = k0+ntk*16+quad*4+reg][qrow] (log2 units)
        f32x4 st[8];
        const f32x4 zz = {0.f, 0.f, 0.f, 0.f};
        #pragma unroll
        for (int ntk = 0; ntk < 8; ntk++) {
            sh8 kf0 = *(const sh8*)&Ks[(quad * 128 + ntk * 16 + col) * 8];
            sh8 kf1 = *(const sh8*)&Ks[((4 + quad) * 128 + ntk * 16 + col) * 8];
            f32x4 a = __builtin_amdgcn_mfma_f32_16x16x32_bf16(kf0, qf[0], zz, 0, 0, 0);
            st[ntk] = __builtin_amdgcn_mfma_f32_16x16x32_bf16(kf1, qf[1], a, 0, 0, 0);
        }

        // ---- softmax over this round's 32 keys (in-lane + cross-quad)
        if (r == R - 1) {  // only the diagonal round needs masking
            #pragma unroll
            for (int ntk = 0; ntk < 8; ntk++)
                #pragma unroll
                for (int reg = 0; reg < 4; reg++)
                    if (k0 + ntk * 16 + quad * 4 + reg > qrow) st[ntk][reg] = -1e30f;
        }
        float cm = -1e30f;
        #pragma unroll
        for (int ntk = 0; ntk < 8; ntk++)
            #pragma unroll
            for (int reg = 0; reg < 4; reg++) cm = fmaxf(cm, st[ntk][reg]);
        cm = fmaxf(cm, __shfl_xor(cm, 16));
        cm = fmaxf(cm, __shfl_xor(cm, 32));
        const float mn = fmaxf(m, cm);
        const float al = exp2f(m - mn);
        float psum = 0.f;
        #pragma unroll
        for (int ntk = 0; ntk < 8; ntk++)
            #pragma unroll
            for (int reg = 0; reg < 4; reg++) {
                const float pv = exp2f(st[ntk][reg] - mn);
                st[ntk][reg] = pv;
                psum += pv;
            }
        psum += __shfl_xor(psum, 16);
        psum += __shfl_xor(psum, 32);
        l = l * al + psum;
        m = mn;

        // ---- rescale O (alpha redistributed to C-layout rows via shfl)
        float alr[4];
        #pragma unroll
        for (int reg = 0; reg < 4; reg++) alr[reg] = __shfl(al, quad * 4 + reg);
        #pragma unroll
        for (int nt = 0; nt < 4; nt++)
            #pragma unroll
            for (int reg = 0; reg < 4; reg++) Oacc[nt][reg] *= alr[reg];

        // ---- P -> LDS (packed dwords), A-layout consumed below
        #pragma unroll
        for (int ntk = 0; ntk < 8; ntk++) {
            *(unsigned*)&Ps[w][col][ntk * 16 + quad * 4]     = pk_bf16(st[ntk][0], st[ntk][1]);
            *(unsigned*)&Ps[w][col][ntk * 16 + quad * 4 + 2] = pk_bf16(st[ntk][2], st[ntk][3]);
        }

        // ---- O += P @ V  (A = P[qrow][key] per-wave LDS, B = V^T[e][key])
        #pragma unroll
        for (int hv = 0; hv < 4; hv++) {
            sh8 pf = *(const sh8*)&Ps[w][col][hv * 32 + quad * 8];
            #pragma unroll
            for (int nt = 0; nt < 4; nt++) {
                sh8 vf = *(const sh8*)&Vs[((hv * 4 + quad) * 64 + nt * 16 + col) * 8];
                Oacc[nt] = __builtin_amdgcn_mfma_f32_16x16x32_bf16(pf, vf, Oacc[nt], 0, 0, 0);
            }
        }
        __syncthreads();   // protect Ks/Vs before next round's staging
    }

    // ---- epilogue
    const float linv = 1.f / l;
    float lr[4];
    #pragma unroll
    for (int reg = 0; reg < 4; reg++) lr[reg] = __shfl(linv, quad * 4 + reg);
    #pragma unroll
    for (int reg = 0; reg < 4; reg++) {
        const int qr = qw + quad * 4 + reg;
        #pragma unroll
        for (int nt = 0; nt < 4; nt++)
            O[((size_t)(b * L + qr) * 8 + h) * 64 + nt * 16 + col] =
                __float2bfloat16(Oacc[nt][reg] * lr[reg]);
    }
}

// ---------------------------------------------------------------------------
// LayerNorm over last dim (512). x = f1 [+ f2] [+ rb]. Dual output.
// ---------------------------------------------------------------------------
__global__ __launch_bounds__(256) void layernorm_k(const float* __restrict__ f1,
                                                   const float* __restrict__ f2,
                                                   const float* __restrict__ rb,
                                                   const float* __restrict__ g,
                                                   const float* __restrict__ bb,
                                                   float* __restrict__ out32,
                                                   __hip_bfloat16* __restrict__ out16)
{
    const int row = blockIdx.x;
    const int t   = threadIdx.x;
    const size_t base = (size_t)row * 512;
    const int i0 = t * 2;

    float a0 = f1[base + i0], a1 = f1[base + i0 + 1];
    if (f2) { a0 += f2[base + i0]; a1 += f2[base + i0 + 1]; }
    if (rb) { a0 += rb[base + i0]; a1 += rb[base + i0 + 1]; }

    float s = a0 + a1, ss = a0 * a0 + a1 * a1;
    #pragma unroll
    for (int off = 32; off > 0; off >>= 1) {
        s  += __shfl_xor(s, off);
        ss += __shfl_xor(ss, off);
    }
    __shared__ float red[16];
    const int lane = t & 63, wid = t >> 6;
    if (lane == 0) { red[wid] = s; red[8 + wid] = ss; }
    __syncthreads();
    if (t == 0) {
        const float S  = red[0] + red[1] + red[2] + red[3];
        const float SS = red[8] + red[9] + red[10] + red[11];
        const float mu = S * (1.f / 512.f);
        const float var = SS * (1.f / 512.f) - mu * mu;
        red[0] = mu;
        red[1] = rsqrtf(fmaxf(var, 0.f) + 1e-5f);
    }
    __syncthreads();
    const float mu = red[0], rstd = red[1];
    const float y0 = (a0 - mu) * rstd * g[i0]     + bb[i0];
    const float y1 = (a1 - mu) * rstd * g[i0 + 1] + bb[i0 + 1];
    if (out32) { out32[base + i0] = y0; out32[base + i0 + 1] = y1; }
    if (out16) { out16[base + i0] = __float2bfloat16(y0); out16[base + i0 + 1] = __float2bfloat16(y1); }
}

// ---------------------------------------------------------------------------
extern "C" void kernel_launch(void* const* d_in, const int* in_sizes, int n_in,
                              void* d_out, int out_size, void* d_ws, size_t ws_size,
                              hipStream_t stream)
{
    const float* q   = (const float*)d_in[0];
    const float* k   = (const float*)d_in[1];
    const float* v   = (const float*)d_in[2];
    const float* Wq  = (const float*)d_in[3];
    const float* bq  = (const float*)d_in[4];
    const float* Wk  = (const float*)d_in[5];
    const float* bk  = (const float*)d_in[6];
    const float* Wv  = (const float*)d_in[7];
    const float* bv  = (const float*)d_in[8];
    const float* Wo  = (const float*)d_in[9];
    const float* bo  = (const float*)d_in[10];
    const float* Wc1 = (const float*)d_in[11];
    const float* bc1 = (const float*)d_in[12];
    const float* Wc2 = (const float*)d_in[13];
    const float* bc2 = (const float*)d_in[14];
    const float* g1  = (const float*)d_in[15];
    const float* b1  = (const float*)d_in[16];
    const float* g2  = (const float*)d_in[17];
    const float* b2  = (const float*)d_in[18];
    const float* Wl  = (const float*)d_in[19];
    const float* bl  = (const float*)d_in[20];
    float* out = (float*)d_out;

    const int B = 4, L = 2048, H = 8;
    const int M = B * L;                        // 8192

    // Byte-offset workspace map (peak 82.3 MB; liveness re-verified R7):
    char* base = (char*)d_ws;
    unsigned short* Wall = (unsigned short*)(base + 0);          // Wq,Wk,Wv,Wo,Wl,Wc1,Wc2 contiguous
    unsigned short* Wob  = (unsigned short*)(base + 1572864);
    unsigned short* Wlb  = (unsigned short*)(base + 2097152);
    unsigned short* Wc1b = (unsigned short*)(base + 2621440);
    unsigned short* Wc2b = (unsigned short*)(base + 4718592);
    float*          X1   = (float*)(base + 6815744);
    unsigned short* X1b  = (unsigned short*)(base + 23592960);
    unsigned short* X2b  = (unsigned short*)(base + 23592960);
    unsigned short* H1   = (unsigned short*)(base + 31981568);
    float*          Y2   = (float*)(base + 65536000);
    float*          A2   = (float*)(base + 31981568);
    unsigned short* A1   = (unsigned short*)(base + 48758784);
    unsigned short* Qb   = (unsigned short*)(base + 57147392);
    unsigned short* Kb   = (unsigned short*)(base + 65536000);
    unsigned short* Vt   = (unsigned short*)(base + 73924608);
    unsigned short* Vb   = (unsigned short*)(base + 6815744);
    unsigned short* qb   = (unsigned short*)(base + 15204352);
    unsigned short* kb   = (unsigned short*)(base + 23592960);
    unsigned short* vb   = (unsigned short*)(base + 31981568);

    const dim3 blk(256);
    const int NQKV = M * 512;                   // 4M elements each

    // 0a: q,k,v fp32->bf16 (one batched launch)
    Cv3 cv;
    cv.s[0] = q;  cv.s[1] = k;  cv.s[2] = v;
    cv.d[0] = qb; cv.d[1] = kb; cv.d[2] = vb;
    conv_qkv<<<dim3(NQKV / 1024, 1, 3), blk, 0, stream>>>(cv, NQKV);
    // 0b: all weights fp32->bf16 (one launch)
    conv_w<<<dim3(3328), blk, 0, stream>>>(Wq, Wk, Wv, Wo, Wl, Wc1, Wc2, Wall);

    // 1: batched QKV projections (z: Q scaled by QSCALE for exp2-domain attn)
    QkvArg qa;
    qa.A0 = qb; qa.A1 = kb; qa.A2 = vb;
    qa.b0 = bq; qa.b1 = bk; qa.b2 = bv;
    qa.C0 = Qb; qa.C1 = Kb; qa.C2 = Vb;
    gemm_qkv<<<dim3(4, 64, 3), blk, 0, stream>>>(qa, Wall, M, 512, 512);

    // 2: V -> [B,H,64,L]
    transpose_v<<<dim3(L / 64, B * H), dim3(64, 4), 0, stream>>>(Vb, Vt, L, H);

    // 3: flash attention v2 -> bf16
    attn_mfma<<<dim3(L / 64, B * H), blk, 0, stream>>>(Qb, Kb, Vt, (__hip_bfloat16*)A1, L);

    // 4: att @ Wo^T + bo -> fp32
    gemm_mfma64<float, false><<<dim3(4, 128), blk, 0, stream>>>(A1, Wob, bo, A2, M, 512, 512);

    // 5: x = LN(v + attO) -> fp32 X1 + bf16 X1b
    layernorm_k<<<dim3(M), blk, 0, stream>>>(A2, nullptr, v, g1, b1, X1, (__hip_bfloat16*)X1b);

    // 6: h1 = relu(x @ Wc1^T + bc1) -> bf16 [M,2048]
    gemm_mfma<__hip_bfloat16, true><<<dim3(16, 64), blk, 0, stream>>>(X1b, Wc1b, bc1, (__hip_bfloat16*)H1, M, 2048, 512);

    // 7: y2 = h1 @ Wc2^T + bc2 -> fp32
    gemm_mfma64<float, false><<<dim3(4, 128), blk, 0, stream>>>(H1, Wc2b, bc2, Y2, M, 512, 2048);

    // 8: x2 = LN(x + y2) -> bf16
    layernorm_k<<<dim3(M), blk, 0, stream>>>(X1, Y2, nullptr, g2, b2, nullptr, (__hip_bfloat16*)X2b);

    // 9: out = x2 @ Wl^T + bl -> fp32 d_out
    gemm_mfma64<float, false><<<dim3(4, 128), blk, 0, stream>>>(X2b, Wlb, bl, out, M, 512, 512);
}

// Round 8
// 434.118 us; speedup vs baseline: 7.5251x; 1.0199x over previous
//
#include <hip/hip_runtime.h>
#include <hip/hip_bf16.h>

// Problem constants: B=4, L=2048, d_model=d_value=512, H=8, E=64, d4=2048.
// External inputs/output fp32 (verified R3/R4). Internal compute: bf16 MFMA.

typedef __attribute__((ext_vector_type(8))) short sh8;    // 8 bf16 (A/B frag)
typedef __attribute__((ext_vector_type(4))) float f32x4;  // C/D frag

#define QSCALE 0.18033688011110543f   // 0.125 * log2(e): folded into Q projection

__device__ __forceinline__ void storeOut(float* p, float v) { *p = v; }
__device__ __forceinline__ void storeOut(__hip_bfloat16* p, float v) { *p = __float2bfloat16(v); }

// async global->LDS, 16 B per lane, wave-uniform LDS base (m97 pattern)
__device__ __forceinline__ void gl_lds16(const unsigned short* g, unsigned short* l) {
    __builtin_amdgcn_global_load_lds((const __attribute__((address_space(1))) void*)g,
                                     (__attribute__((address_space(3))) void*)l, 16, 0, 0);
}

// pack two fp32 into one dword of two bf16 (RNE)
__device__ __forceinline__ unsigned pk_bf16(float a, float b) {
    __hip_bfloat162 h = __float22bfloat162_rn(make_float2(a, b));
    return *(unsigned*)&h;
}

// ---------------------------------------------------------------------------
// One launch: all fp32 -> bf16 converts. z=0,1,2: q,k,v. z=3: the 7 weights
// packed contiguously (Wq,Wk,Wv,Wo,Wl,Wc1,Wc2; 3407872 elements total).
// ---------------------------------------------------------------------------
struct CvAll {
    const float* s[3]; unsigned short* d[3];
    const float* w[7]; unsigned short* wd;
};
__global__ __launch_bounds__(256) void conv_all(CvAll p, int n)
{
    const int z = blockIdx.z;
    const int i = (blockIdx.x * 256 + threadIdx.x) * 4;
    if (z < 3) {
        if (i < n) {
            const float4 v = *(const float4*)(p.s[z] + i);
            *(uint2*)(p.d[z] + i) = make_uint2(pk_bf16(v.x, v.y), pk_bf16(v.z, v.w));
        }
    } else {
        if (i >= 3407872) return;
        const float* s; int off;
        if      (i < 262144)  { s = p.w[0]; off = i; }
        else if (i < 524288)  { s = p.w[1]; off = i - 262144; }
        else if (i < 786432)  { s = p.w[2]; off = i - 524288; }
        else if (i < 1048576) { s = p.w[3]; off = i - 786432; }
        else if (i < 1310720) { s = p.w[4]; off = i - 1048576; }
        else if (i < 2359296) { s = p.w[5]; off = i - 1310720; }
        else                  { s = p.w[6]; off = i - 2359296; }
        const float4 v = *(const float4*)(s + off);
        *(uint2*)(p.wd + i) = make_uint2(pk_bf16(v.x, v.y), pk_bf16(v.z, v.w));
    }
}

// ---------------------------------------------------------------------------
// MFMA GEMM 128x128, BK=64: C = A @ W^T + bias, opt ReLU. fp32 accumulate.
// LDS 32 KB; 8 staging instr/wave + 32 MFMA per k-iter (half the barriers
// of BK=32 for these small-K shapes).
// ---------------------------------------------------------------------------
template <typename TOUT, bool RELU>
__global__ __launch_bounds__(256) void gemm_mfma(const unsigned short* __restrict__ A,
                                                 const unsigned short* __restrict__ W,
                                                 const float* __restrict__ bias,
                                                 TOUT* __restrict__ C,
                                                 int M, int N, int K)
{
    __shared__ unsigned short AsL[8192];   // [q:8][row:128][8]
    __shared__ unsigned short BsL[8192];
    const int t    = threadIdx.x;
    const int wave = t >> 6, lane = t & 63;
    const int quad = lane >> 4, col = lane & 15;
    const int wm   = wave >> 1, wn = wave & 1;
    const int m0   = blockIdx.y * 128, n0 = blockIdx.x * 128;

    f32x4 acc[4][4];
    #pragma unroll
    for (int mt = 0; mt < 4; mt++)
        #pragma unroll
        for (int nt = 0; nt < 4; nt++)
            acc[mt][nt] = (f32x4){0.f, 0.f, 0.f, 0.f};

    for (int k0 = 0; k0 < K; k0 += 64) {
        #pragma unroll
        for (int seg = 0; seg < 4; seg++) {
            const int s0 = seg * 256 + wave * 64;
            const int s  = s0 + lane;
            const int r  = s & 127, q = s >> 7;
            gl_lds16(A + (size_t)(m0 + r) * K + k0 + q * 8, &AsL[s0 * 8]);
            gl_lds16(W + (size_t)(n0 + r) * K + k0 + q * 8, &BsL[s0 * 8]);
        }
        __syncthreads();
        #pragma unroll
        for (int kc = 0; kc < 2; kc++) {
            sh8 af[4], bf[4];
            #pragma unroll
            for (int mt = 0; mt < 4; mt++)
                af[mt] = *(const sh8*)&AsL[((kc * 4 + quad) * 128 + wm * 64 + mt * 16 + col) * 8];
            #pragma unroll
            for (int nt = 0; nt < 4; nt++)
                bf[nt] = *(const sh8*)&BsL[((kc * 4 + quad) * 128 + wn * 64 + nt * 16 + col) * 8];
            #pragma unroll
            for (int mt = 0; mt < 4; mt++)
                #pragma unroll
                for (int nt = 0; nt < 4; nt++)
                    acc[mt][nt] = __builtin_amdgcn_mfma_f32_16x16x32_bf16(af[mt], bf[nt], acc[mt][nt], 0, 0, 0);
        }
        __syncthreads();
    }
    #pragma unroll
    for (int nt = 0; nt < 4; nt++) {
        const int cn = n0 + wn * 64 + nt * 16 + col;
        const float bj = bias[cn];
        #pragma unroll
        for (int mt = 0; mt < 4; mt++) {
            const int rm = m0 + wm * 64 + mt * 16 + quad * 4;
            #pragma unroll
            for (int reg = 0; reg < 4; reg++) {
                float cv = acc[mt][nt][reg] + bj;
                if (RELU) cv = fmaxf(cv, 0.f);
                storeOut(&C[(size_t)(rm + reg) * N + cn], cv);
            }
        }
    }
}

// ---------------------------------------------------------------------------
// Batched QKV GEMM (grid.z = 0,1,2), BK=64. z=0 (Q) scaled by QSCALE
// (exp2-domain attention).
// ---------------------------------------------------------------------------
struct QkvArg {
    const unsigned short *A0, *A1, *A2;
    const float *b0, *b1, *b2;
    unsigned short *C0, *C1, *C2;
};
__global__ __launch_bounds__(256) void gemm_qkv(QkvArg ar, const unsigned short* __restrict__ Wall,
                                                int M, int N, int K)
{
    const int z = blockIdx.z;
    const unsigned short* A = z == 0 ? ar.A0 : (z == 1 ? ar.A1 : ar.A2);
    const unsigned short* W = Wall + (size_t)z * 262144;
    const float* bias = z == 0 ? ar.b0 : (z == 1 ? ar.b1 : ar.b2);
    unsigned short* C = z == 0 ? ar.C0 : (z == 1 ? ar.C1 : ar.C2);
    const float scale = z == 0 ? QSCALE : 1.0f;

    __shared__ unsigned short AsL[8192];
    __shared__ unsigned short BsL[8192];
    const int t    = threadIdx.x;
    const int wave = t >> 6, lane = t & 63;
    const int quad = lane >> 4, col = lane & 15;
    const int wm   = wave >> 1, wn = wave & 1;
    const int m0   = blockIdx.y * 128, n0 = blockIdx.x * 128;

    f32x4 acc[4][4];
    #pragma unroll
    for (int mt = 0; mt < 4; mt++)
        #pragma unroll
        for (int nt = 0; nt < 4; nt++)
            acc[mt][nt] = (f32x4){0.f, 0.f, 0.f, 0.f};

    for (int k0 = 0; k0 < K; k0 += 64) {
        #pragma unroll
        for (int seg = 0; seg < 4; seg++) {
            const int s0 = seg * 256 + wave * 64;
            const int s  = s0 + lane;
            const int r  = s & 127, q = s >> 7;
            gl_lds16(A + (size_t)(m0 + r) * K + k0 + q * 8, &AsL[s0 * 8]);
            gl_lds16(W + (size_t)(n0 + r) * K + k0 + q * 8, &BsL[s0 * 8]);
        }
        __syncthreads();
        #pragma unroll
        for (int kc = 0; kc < 2; kc++) {
            sh8 af[4], bf[4];
            #pragma unroll
            for (int mt = 0; mt < 4; mt++)
                af[mt] = *(const sh8*)&AsL[((kc * 4 + quad) * 128 + wm * 64 + mt * 16 + col) * 8];
            #pragma unroll
            for (int nt = 0; nt < 4; nt++)
                bf[nt] = *(const sh8*)&BsL[((kc * 4 + quad) * 128 + wn * 64 + nt * 16 + col) * 8];
            #pragma unroll
            for (int mt = 0; mt < 4; mt++)
                #pragma unroll
                for (int nt = 0; nt < 4; nt++)
                    acc[mt][nt] = __builtin_amdgcn_mfma_f32_16x16x32_bf16(af[mt], bf[nt], acc[mt][nt], 0, 0, 0);
        }
        __syncthreads();
    }
    #pragma unroll
    for (int nt = 0; nt < 4; nt++) {
        const int cn = n0 + wn * 64 + nt * 16 + col;
        const float bj = bias[cn];
        #pragma unroll
        for (int mt = 0; mt < 4; mt++) {
            const int rm = m0 + wm * 64 + mt * 16 + quad * 4;
            #pragma unroll
            for (int reg = 0; reg < 4; reg++)
                C[(size_t)(rm + reg) * N + cn] =
                    (unsigned short)__bfloat16_as_ushort(__float2bfloat16((acc[mt][nt][reg] + bj) * scale));
        }
    }
}

// ---------------------------------------------------------------------------
// MFMA GEMM 64x128 tile, BK=64 (for N=512 shapes: 512 blocks = 2/CU).
// ---------------------------------------------------------------------------
template <typename TOUT, bool RELU>
__global__ __launch_bounds__(256) void gemm_mfma64(const unsigned short* __restrict__ A,
                                                   const unsigned short* __restrict__ W,
                                                   const float* __restrict__ bias,
                                                   TOUT* __restrict__ C,
                                                   int M, int N, int K)
{
    __shared__ unsigned short AsL[4096];   // [q:8][row:64][8]
    __shared__ unsigned short BsL[8192];   // [q:8][row:128][8]
    const int t    = threadIdx.x;
    const int wave = t >> 6, lane = t & 63;
    const int quad = lane >> 4, col = lane & 15;
    const int wm   = wave >> 1, wn = wave & 1;
    const int m0   = blockIdx.y * 64, n0 = blockIdx.x * 128;

    f32x4 acc[2][4];
    #pragma unroll
    for (int mt = 0; mt < 2; mt++)
        #pragma unroll
        for (int nt = 0; nt < 4; nt++)
            acc[mt][nt] = (f32x4){0.f, 0.f, 0.f, 0.f};

    for (int k0 = 0; k0 < K; k0 += 64) {
        #pragma unroll
        for (int seg = 0; seg < 2; seg++) {       // A: 512 slots
            const int s0 = seg * 256 + wave * 64;
            const int s  = s0 + lane;
            const int r  = s & 63, q = s >> 6;
            gl_lds16(A + (size_t)(m0 + r) * K + k0 + q * 8, &AsL[s0 * 8]);
        }
        #pragma unroll
        for (int seg = 0; seg < 4; seg++) {       // B: 1024 slots
            const int s0 = seg * 256 + wave * 64;
            const int s  = s0 + lane;
            const int r  = s & 127, q = s >> 7;
            gl_lds16(W + (size_t)(n0 + r) * K + k0 + q * 8, &BsL[s0 * 8]);
        }
        __syncthreads();
        #pragma unroll
        for (int kc = 0; kc < 2; kc++) {
            sh8 af[2], bf[4];
            #pragma unroll
            for (int mt = 0; mt < 2; mt++)
                af[mt] = *(const sh8*)&AsL[((kc * 4 + quad) * 64 + wm * 32 + mt * 16 + col) * 8];
            #pragma unroll
            for (int nt = 0; nt < 4; nt++)
                bf[nt] = *(const sh8*)&BsL[((kc * 4 + quad) * 128 + wn * 64 + nt * 16 + col) * 8];
            #pragma unroll
            for (int mt = 0; mt < 2; mt++)
                #pragma unroll
                for (int nt = 0; nt < 4; nt++)
                    acc[mt][nt] = __builtin_amdgcn_mfma_f32_16x16x32_bf16(af[mt], bf[nt], acc[mt][nt], 0, 0, 0);
        }
        __syncthreads();
    }
    #pragma unroll
    for (int nt = 0; nt < 4; nt++) {
        const int cn = n0 + wn * 64 + nt * 16 + col;
        const float bj = bias[cn];
        #pragma unroll
        for (int mt = 0; mt < 2; mt++) {
            const int rm = m0 + wm * 32 + mt * 16 + quad * 4;
            #pragma unroll
            for (int reg = 0; reg < 4; reg++) {
                float cv = acc[mt][nt][reg] + bj;
                if (RELU) cv = fmaxf(cv, 0.f);
                storeOut(&C[(size_t)(rm + reg) * N + cn], cv);
            }
        }
    }
}

// ---------------------------------------------------------------------------
// Transpose V projection (bf16): [B,S,H,64] -> [B,H,64,S].
// ---------------------------------------------------------------------------
__global__ __launch_bounds__(256) void transpose_v(const unsigned short* __restrict__ Vb,
                                                   unsigned short* __restrict__ Vt,
                                                   int L, int H)
{
    __shared__ unsigned short tile[64][65];
    const int s0 = blockIdx.x * 64;
    const int bh = blockIdx.y;
    const int b  = bh / H, h = bh % H;
    const int tx = threadIdx.x, ty = threadIdx.y;
    #pragma unroll
    for (int i = 0; i < 16; i++) {
        const int sl = ty * 16 + i;
        tile[sl][tx] = Vb[((size_t)(b * L + s0 + sl) * H + h) * 64 + tx];
    }
    __syncthreads();
    #pragma unroll
    for (int i = 0; i < 16; i++) {
        const int el = ty * 16 + i;
        Vt[((size_t)bh * 64 + el) * L + s0 + tx] = tile[tx][el];
    }
}

// ---------------------------------------------------------------------------
// MFMA flash attention v3 (causal, load-balanced). Block = 4 waves.
// Each block owns TWO query tiles paired (j, 31-j): constant compute per
// block (R_A + R_B = 17 rounds of 32 MFMA), one K/V staging serves both
// tiles (K-fragments reused). S^T layout (lane owns one qrow), exp2 domain
// (QSCALE folded into Q projection), mask only last active round per tile.
// Qb/Kb: [B,L,H,64] bf16; Vt: [B*H,64,L] bf16; O: [B,L,H,64] bf16.
// ---------------------------------------------------------------------------
__global__ __launch_bounds__(256) void attn_mfma(const unsigned short* __restrict__ Qb,
                                                 const unsigned short* __restrict__ Kb,
                                                 const unsigned short* __restrict__ Vt,
                                                 __hip_bfloat16* __restrict__ O,
                                                 int L)
{
    __shared__ unsigned short Ks[8192];        // [q=e/8:8][key:128][8]  16 KB
    __shared__ unsigned short Vs[8192];        // [kq=key/8:16][e:64][8] 16 KB
    __shared__ unsigned short Ps[4][16][136];  // per wave [qrow:16][key:128+pad]

    const int j    = blockIdx.x;                     // 0..15
    const int bh   = blockIdx.y;
    const int b    = bh >> 3, h = bh & 7;            // H = 8
    const int t    = threadIdx.x;
    const int w    = t >> 6, lane = t & 63;
    const int quad = lane >> 4, col = lane & 15;

    const int qtA = j, qtB = 31 - j;                 // L/64 - 1 = 31
    const int RA  = (qtA + 2) >> 1;                  // 128-key rounds, tile A
    const int RB  = (qtB + 2) >> 1;
    const int qrowA = qtA * 64 + w * 16 + col;
    const int qrowB = qtB * 64 + w * 16 + col;

    // Q B-frags (QSCALE pre-applied in projection)
    sh8 qfA[2], qfB[2];
    {
        const size_t qa = ((size_t)(b * L + qrowA) * 8 + h) * 64;
        qfA[0] = *(const sh8*)(Qb + qa + quad * 8);
        qfA[1] = *(const sh8*)(Qb + qa + 32 + quad * 8);
        const size_t qb2 = ((size_t)(b * L + qrowB) * 8 + h) * 64;
        qfB[0] = *(const sh8*)(Qb + qb2 + quad * 8);
        qfB[1] = *(const sh8*)(Qb + qb2 + 32 + quad * 8);
    }

    f32x4 OA[4], OB[4];
    #pragma unroll
    for (int nt = 0; nt < 4; nt++) { OA[nt] = (f32x4){0.f,0.f,0.f,0.f}; OB[nt] = (f32x4){0.f,0.f,0.f,0.f}; }
    float mA = -1e30f, lA = 0.f, mB = -1e30f, lB = 0.f;

    // softmax + P write + PV accumulate for one tile's st
    auto soft_pv = [&](f32x4* st, f32x4* Oacc, float& m, float& l,
                       int qrow, int k0, bool maskRound) {
        if (maskRound) {
            #pragma unroll
            for (int ntk = 0; ntk < 8; ntk++)
                #pragma unroll
                for (int reg = 0; reg < 4; reg++)
                    if (k0 + ntk * 16 + quad * 4 + reg > qrow) st[ntk][reg] = -1e30f;
        }
        float cm = -1e30f;
        #pragma unroll
        for (int ntk = 0; ntk < 8; ntk++)
            #pragma unroll
            for (int reg = 0; reg < 4; reg++) cm = fmaxf(cm, st[ntk][reg]);
        cm = fmaxf(cm, __shfl_xor(cm, 16));
        cm = fmaxf(cm, __shfl_xor(cm, 32));
        const float mn = fmaxf(m, cm);
        const float al = exp2f(m - mn);
        float psum = 0.f;
        #pragma unroll
        for (int ntk = 0; ntk < 8; ntk++)
            #pragma unroll
            for (int reg = 0; reg < 4; reg++) {
                const float pv = exp2f(st[ntk][reg] - mn);
                st[ntk][reg] = pv;
                psum += pv;
            }
        psum += __shfl_xor(psum, 16);
        psum += __shfl_xor(psum, 32);
        l = l * al + psum;
        m = mn;
        float alr[4];
        #pragma unroll
        for (int reg = 0; reg < 4; reg++) alr[reg] = __shfl(al, quad * 4 + reg);
        #pragma unroll
        for (int nt = 0; nt < 4; nt++)
            #pragma unroll
            for (int reg = 0; reg < 4; reg++) Oacc[nt][reg] *= alr[reg];
        #pragma unroll
        for (int ntk = 0; ntk < 8; ntk++)
            *(uint2*)&Ps[w][col][ntk * 16 + quad * 4] =
                make_uint2(pk_bf16(st[ntk][0], st[ntk][1]), pk_bf16(st[ntk][2], st[ntk][3]));
        #pragma unroll
        for (int hv = 0; hv < 4; hv++) {
            sh8 pf = *(const sh8*)&Ps[w][col][hv * 32 + quad * 8];
            #pragma unroll
            for (int nt = 0; nt < 4; nt++) {
                sh8 vf = *(const sh8*)&Vs[((hv * 4 + quad) * 64 + nt * 16 + col) * 8];
                Oacc[nt] = __builtin_amdgcn_mfma_f32_16x16x32_bf16(pf, vf, Oacc[nt], 0, 0, 0);
            }
        }
    };

    for (int r = 0; r < RB; r++) {
        const int k0 = r * 128;
        // ---- async staging (no clamps: k0+127 <= 2047 by construction)
        #pragma unroll
        for (int seg = 0; seg < 4; seg++) {
            const int s0 = seg * 256 + w * 64;
            const int s  = s0 + lane;
            {   const int q = s >> 7, key = s & 127;
                gl_lds16(Kb + ((size_t)(b * L + k0 + key) * 8 + h) * 64 + q * 8, &Ks[s0 * 8]); }
            {   const int kq = s >> 6, e = s & 63;
                gl_lds16(Vt + ((size_t)bh * 64 + e) * L + k0 + kq * 8, &Vs[s0 * 8]); }
        }
        __syncthreads();

        const bool actA = (r < RA);
        // ---- S^T for both tiles, K-fragments loaded once
        f32x4 stA[8], stB[8];
        const f32x4 zz = {0.f, 0.f, 0.f, 0.f};
        #pragma unroll
        for (int ntk = 0; ntk < 8; ntk++) {
            sh8 kf0 = *(const sh8*)&Ks[(quad * 128 + ntk * 16 + col) * 8];
            sh8 kf1 = *(const sh8*)&Ks[((4 + quad) * 128 + ntk * 16 + col) * 8];
            f32x4 a = __builtin_amdgcn_mfma_f32_16x16x32_bf16(kf0, qfB[0], zz, 0, 0, 0);
            stB[ntk] = __builtin_amdgcn_mfma_f32_16x16x32_bf16(kf1, qfB[1], a, 0, 0, 0);
            if (actA) {
                f32x4 a2 = __builtin_amdgcn_mfma_f32_16x16x32_bf16(kf0, qfA[0], zz, 0, 0, 0);
                stA[ntk] = __builtin_amdgcn_mfma_f32_16x16x32_bf16(kf1, qfA[1], a2, 0, 0, 0);
            }
        }
        soft_pv(stB, OB, mB, lB, qrowB, k0, r == RB - 1);
        if (actA) soft_pv(stA, OA, mA, lA, qrowA, k0, r == RA - 1);
        __syncthreads();
    }

    // ---- epilogues
    {
        const float li = 1.f / lA;
        float lr[4];
        #pragma unroll
        for (int reg = 0; reg < 4; reg++) lr[reg] = __shfl(li, quad * 4 + reg);
        #pragma unroll
        for (int reg = 0; reg < 4; reg++) {
            const int qr = qtA * 64 + w * 16 + quad * 4 + reg;
            #pragma unroll
            for (int nt = 0; nt < 4; nt++)
                O[((size_t)(b * L + qr) * 8 + h) * 64 + nt * 16 + col] =
                    __float2bfloat16(OA[nt][reg] * lr[reg]);
        }
    }
    {
        const float li = 1.f / lB;
        float lr[4];
        #pragma unroll
        for (int reg = 0; reg < 4; reg++) lr[reg] = __shfl(li, quad * 4 + reg);
        #pragma unroll
        for (int reg = 0; reg < 4; reg++) {
            const int qr = qtB * 64 + w * 16 + quad * 4 + reg;
            #pragma unroll
            for (int nt = 0; nt < 4; nt++)
                O[((size_t)(b * L + qr) * 8 + h) * 64 + nt * 16 + col] =
                    __float2bfloat16(OB[nt][reg] * lr[reg]);
        }
    }
}

// ---------------------------------------------------------------------------
// LayerNorm over last dim (512). x = f1 [+ f2] [+ rb]. Dual output.
// ---------------------------------------------------------------------------
__global__ __launch_bounds__(256) void layernorm_k(const float* __restrict__ f1,
                                                   const float* __restrict__ f2,
                                                   const float* __restrict__ rb,
                                                   const float* __restrict__ g,
                                                   const float* __restrict__ bb,
                                                   float* __restrict__ out32,
                                                   __hip_bfloat16* __restrict__ out16)
{
    const int row = blockIdx.x;
    const int t   = threadIdx.x;
    const size_t base = (size_t)row * 512;
    const int i0 = t * 2;

    float a0 = f1[base + i0], a1 = f1[base + i0 + 1];
    if (f2) { a0 += f2[base + i0]; a1 += f2[base + i0 + 1]; }
    if (rb) { a0 += rb[base + i0]; a1 += rb[base + i0 + 1]; }

    float s = a0 + a1, ss = a0 * a0 + a1 * a1;
    #pragma unroll
    for (int off = 32; off > 0; off >>= 1) {
        s  += __shfl_xor(s, off);
        ss += __shfl_xor(ss, off);
    }
    __shared__ float red[16];
    const int lane = t & 63, wid = t >> 6;
    if (lane == 0) { red[wid] = s; red[8 + wid] = ss; }
    __syncthreads();
    if (t == 0) {
        const float S  = red[0] + red[1] + red[2] + red[3];
        const float SS = red[8] + red[9] + red[10] + red[11];
        const float mu = S * (1.f / 512.f);
        const float var = SS * (1.f / 512.f) - mu * mu;
        red[0] = mu;
        red[1] = rsqrtf(fmaxf(var, 0.f) + 1e-5f);
    }
    __syncthreads();
    const float mu = red[0], rstd = red[1];
    const float y0 = (a0 - mu) * rstd * g[i0]     + bb[i0];
    const float y1 = (a1 - mu) * rstd * g[i0 + 1] + bb[i0 + 1];
    if (out32) { out32[base + i0] = y0; out32[base + i0 + 1] = y1; }
    if (out16) { out16[base + i0] = __float2bfloat16(y0); out16[base + i0 + 1] = __float2bfloat16(y1); }
}

// ---------------------------------------------------------------------------
extern "C" void kernel_launch(void* const* d_in, const int* in_sizes, int n_in,
                              void* d_out, int out_size, void* d_ws, size_t ws_size,
                              hipStream_t stream)
{
    const float* q   = (const float*)d_in[0];
    const float* k   = (const float*)d_in[1];
    const float* v   = (const float*)d_in[2];
    const float* Wq  = (const float*)d_in[3];
    const float* bq  = (const float*)d_in[4];
    const float* Wk  = (const float*)d_in[5];
    const float* bk  = (const float*)d_in[6];
    const float* Wv  = (const float*)d_in[7];
    const float* bv  = (const float*)d_in[8];
    const float* Wo  = (const float*)d_in[9];
    const float* bo  = (const float*)d_in[10];
    const float* Wc1 = (const float*)d_in[11];
    const float* bc1 = (const float*)d_in[12];
    const float* Wc2 = (const float*)d_in[13];
    const float* bc2 = (const float*)d_in[14];
    const float* g1  = (const float*)d_in[15];
    const float* b1  = (const float*)d_in[16];
    const float* g2  = (const float*)d_in[17];
    const float* b2  = (const float*)d_in[18];
    const float* Wl  = (const float*)d_in[19];
    const float* bl  = (const float*)d_in[20];
    float* out = (float*)d_out;

    const int B = 4, L = 2048, H = 8;
    const int M = B * L;                        // 8192

    // Byte-offset workspace map (peak 82.3 MB; liveness verified R7):
    char* base = (char*)d_ws;
    unsigned short* Wall = (unsigned short*)(base + 0);          // Wq,Wk,Wv,Wo,Wl,Wc1,Wc2
    unsigned short* Wob  = (unsigned short*)(base + 1572864);
    unsigned short* Wlb  = (unsigned short*)(base + 2097152);
    unsigned short* Wc1b = (unsigned short*)(base + 2621440);
    unsigned short* Wc2b = (unsigned short*)(base + 4718592);
    float*          X1   = (float*)(base + 6815744);
    unsigned short* X1b  = (unsigned short*)(base + 23592960);
    unsigned short* X2b  = (unsigned short*)(base + 23592960);
    unsigned short* H1   = (unsigned short*)(base + 31981568);
    float*          Y2   = (float*)(base + 65536000);
    float*          A2   = (float*)(base + 31981568);
    unsigned short* A1   = (unsigned short*)(base + 48758784);
    unsigned short* Qb   = (unsigned short*)(base + 57147392);
    unsigned short* Kb   = (unsigned short*)(base + 65536000);
    unsigned short* Vt   = (unsigned short*)(base + 73924608);
    unsigned short* Vb   = (unsigned short*)(base + 6815744);
    unsigned short* qb   = (unsigned short*)(base + 15204352);
    unsigned short* kb   = (unsigned short*)(base + 23592960);
    unsigned short* vb   = (unsigned short*)(base + 31981568);

    const dim3 blk(256);
    const int NQKV = M * 512;                   // 4M elements each

    // 0: all converts, one launch (z=0..2: q,k,v; z=3: weights)
    CvAll cv;
    cv.s[0] = q;  cv.s[1] = k;  cv.s[2] = v;
    cv.d[0] = qb; cv.d[1] = kb; cv.d[2] = vb;
    cv.w[0] = Wq; cv.w[1] = Wk; cv.w[2] = Wv; cv.w[3] = Wo; cv.w[4] = Wl;
    cv.w[5] = Wc1; cv.w[6] = Wc2; cv.wd = Wall;
    conv_all<<<dim3(NQKV / 1024, 1, 4), blk, 0, stream>>>(cv, NQKV);

    // 1: batched QKV projections (Q scaled by QSCALE)
    QkvArg qa;
    qa.A0 = qb; qa.A1 = kb; qa.A2 = vb;
    qa.b0 = bq; qa.b1 = bk; qa.b2 = bv;
    qa.C0 = Qb; qa.C1 = Kb; qa.C2 = Vb;
    gemm_qkv<<<dim3(4, 64, 3), blk, 0, stream>>>(qa, Wall, M, 512, 512);

    // 2: V -> [B,H,64,L]
    transpose_v<<<dim3(L / 64, B * H), dim3(64, 4), 0, stream>>>(Vb, Vt, L, H);

    // 3: flash attention v3 (causal-paired, balanced) -> bf16
    attn_mfma<<<dim3(L / 128, B * H), blk, 0, stream>>>(Qb, Kb, Vt, (__hip_bfloat16*)A1, L);

    // 4: att @ Wo^T + bo -> fp32
    gemm_mfma64<float, false><<<dim3(4, 128), blk, 0, stream>>>(A1, Wob, bo, A2, M, 512, 512);

    // 5: x = LN(v + attO) -> fp32 X1 + bf16 X1b
    layernorm_k<<<dim3(M), blk, 0, stream>>>(A2, nullptr, v, g1, b1, X1, (__hip_bfloat16*)X1b);

    // 6: h1 = relu(x @ Wc1^T + bc1) -> bf16 [M,2048]
    gemm_mfma<__hip_bfloat16, true><<<dim3(16, 64), blk, 0, stream>>>(X1b, Wc1b, bc1, (__hip_bfloat16*)H1, M, 2048, 512);

    // 7: y2 = h1 @ Wc2^T + bc2 -> fp32
    gemm_mfma64<float, false><<<dim3(4, 128), blk, 0, stream>>>(H1, Wc2b, bc2, Y2, M, 512, 2048);

    // 8: x2 = LN(x + y2) -> bf16
    layernorm_k<<<dim3(M), blk, 0, stream>>>(X1, Y2, nullptr, g2, b2, nullptr, (__hip_bfloat16*)X2b);

    // 9: out = x2 @ Wl^T + bl -> fp32 d_out
    gemm_mfma64<float, false><<<dim3(4, 128), blk, 0, stream>>>(X2b, Wlb, bl, out, M, 512, 512);
}